// Round 1
// baseline (576.160 us; speedup 1.0000x reference)
//
#include <hip/hip_runtime.h>

#define D_MODEL 512
#define D_FF    2048
#define NEXP    8
#define TOKENS  8192
#define TROWS   26368     // 8192 universal + <=18176 expert slots padded to 256

typedef __bf16 bf16_t;
typedef __attribute__((ext_vector_type(8))) __bf16 bf16x8_t;
typedef __attribute__((ext_vector_type(4))) __bf16 bf16x4_t;
typedef __attribute__((ext_vector_type(4))) float  f32x4_t;

// ---- workspace layout (bytes) ----
#define W1P_OFF    0u            // bf16 [8][16][2048][32]
#define UW1P_OFF   16777216u     // bf16 [16][2048][32]
#define W2P_OFF    18874368u     // bf16 [8][64][512][32]
#define UW2P_OFF   35651584u     // bf16 [64][512][32]
#define CNT_OFF    37748736u     // int[16]
#define TOKL_OFF   37748800u     // int  [8][8192]
#define GATEL_OFF  38010944u     // float[8][8192]
#define OMEGA_OFF  38273088u     // float[8192]
#define TLOG_OFF   38305856u     // double[8][8]
#define SOFF_OFF   38306368u     // int[16]
#define SPC_OFF    38306432u     // int[16]
#define RMETA_OFF  38306496u     // int[TROWS]
#define RGATE_OFF  38411968u     // float[TROWS]
#define XGP_OFF    38517440u     // bf16 [16][TROWS][32]  (26,999,808 B)
#define S0_OFF     38517440u     // ALIAS of XGP (xgp dead before gemm2 writes s0/s1)
#define S1_OFF     46906048u     // ALIAS of XGP
#define HP_OFF     65517248u     // bf16 [64][TROWS][32]  (107,999,232 B)
#define TOKE_OFF   173516480u    // int[8192]
#define TG_OFF     173549248u    // float2[8192]
// end = 173,614,784 bytes (< previous 186.5 MB footprint)

__device__ inline f32x4_t mfma_bf16(bf16x8_t a, bf16x8_t b, f32x4_t c) {
  return __builtin_amdgcn_mfma_f32_16x16x32_bf16(a, b, c, 0, 0, 0);
}

__device__ __forceinline__ void load_lds16(const void* g, void* l) {
  __builtin_amdgcn_global_load_lds(
      (const __attribute__((address_space(1))) unsigned int*)g,
      (__attribute__((address_space(3))) unsigned int*)l, 16, 0, 0);
}

// fast gelu: max abs err ~3e-4 << bf16 quantum
__device__ __forceinline__ float fast_gelu(float x) {
  float z = 0.7978845608f * (x + 0.044715f * x * x * x);
  float u = __expf(2.0f * z);
  float th = (u - 1.0f) * __builtin_amdgcn_rcpf(u + 1.0f);
  return 0.5f * x * (1.0f + th);
}

// pack in[R][C] f32 -> out[R/32][C][32] bf16
__global__ void k_pack(const float* __restrict__ in, bf16_t* __restrict__ out, int R, int C) {
  __shared__ float tile[64][65];
  const size_t mat = (size_t)blockIdx.z * R * C;
  in  += mat;
  out += mat;
  int r0 = blockIdx.y * 64, c0 = blockIdx.x * 64;
  for (int i = threadIdx.x; i < 4096; i += 256) {
    int r = i >> 6, c = i & 63;
    tile[r][c] = in[(size_t)(r0 + r) * C + c0 + c];
  }
  __syncthreads();
  int item = threadIdx.x >> 1, jh = threadIdx.x & 1;
  int c = item & 63, s = item >> 6;
  union { bf16_t h[16]; uint4 u[2]; } t;
#pragma unroll
  for (int k = 0; k < 16; k++) t.h[k] = (bf16_t)tile[s * 32 + jh * 16 + k][c];
  char* dst = (char*)out + ((size_t)((r0 >> 5) + s) * C + (c0 + c)) * 64 + jh * 32;
  ((uint4*)dst)[0] = t.u[0];
  ((uint4*)dst)[1] = t.u[1];
}

__global__ void k_tlog(const int* __restrict__ task_ids, const float* __restrict__ task_emb,
                       const float* __restrict__ gate_w, const float* __restrict__ gate_b,
                       double* __restrict__ tlog) {
  int i = threadIdx.x;
  if (i >= 64) return;
  int b = i >> 3, e = i & 7;
  const float* te = task_emb + (size_t)task_ids[b] * D_MODEL;
  double acc = (double)gate_b[e];
  for (int d = 0; d < D_MODEL; d++)
    acc += (double)te[d] * (double)gate_w[(size_t)(D_MODEL + d) * NEXP + e];
  tlog[i] = acc;
}

// one wave per token: f64 logits, top-2 softmax
__global__ void k_gate(const float* __restrict__ x, const float* __restrict__ gate_w,
                       const double* __restrict__ tlog,
                       float* __restrict__ logits_out,
                       int* __restrict__ toke, float2* __restrict__ tg,
                       float* __restrict__ omega) {
  int gtid = blockIdx.x * blockDim.x + threadIdx.x;
  int t = gtid >> 6;
  int lane = gtid & 63;
  if (t >= TOKENS) return;
  const float* xr = x + (size_t)t * D_MODEL;
  int d0 = lane * 8;
  float4 xa = *(const float4*)(xr + d0);
  float4 xc = *(const float4*)(xr + d0 + 4);
  float xv[8] = {xa.x, xa.y, xa.z, xa.w, xc.x, xc.y, xc.z, xc.w};
  double acc[NEXP];
#pragma unroll
  for (int e = 0; e < NEXP; e++) acc[e] = 0.0;
#pragma unroll
  for (int j = 0; j < 8; j++) {
    const float* gwr = gate_w + (size_t)(d0 + j) * NEXP;
    float4 g0 = *(const float4*)gwr;
    float4 g1 = *(const float4*)(gwr + 4);
    double xd = (double)xv[j];
    acc[0] += xd * (double)g0.x; acc[1] += xd * (double)g0.y;
    acc[2] += xd * (double)g0.z; acc[3] += xd * (double)g0.w;
    acc[4] += xd * (double)g1.x; acc[5] += xd * (double)g1.y;
    acc[6] += xd * (double)g1.z; acc[7] += xd * (double)g1.w;
  }
#pragma unroll
  for (int off = 32; off > 0; off >>= 1) {
#pragma unroll
    for (int e = 0; e < NEXP; e++) acc[e] += __shfl_xor(acc[e], off);
  }
  if (lane == 0) {
    int b = t >> 10;
    double lg[NEXP];
#pragma unroll
    for (int e = 0; e < NEXP; e++) {
      lg[e] = acc[e] + tlog[b * NEXP + e];
      logits_out[(size_t)t * NEXP + e] = (float)lg[e];
    }
    int e0 = 0;
    for (int e = 1; e < NEXP; e++) if (lg[e] > lg[e0]) e0 = e;
    int e1 = (e0 == 0) ? 1 : 0;
    for (int e = 0; e < NEXP; e++) if (e != e0 && lg[e] > lg[e1]) e1 = e;
    double p0 = 1.0 / (1.0 + exp(lg[e1] - lg[e0]));
    float g0f = (float)p0;
    float g1f = (float)(1.0 - p0);
    omega[t] = 1.0f - g0f;
    toke[t] = e0 | (e1 << 8);
    tg[t] = float2{g0f, g1f};
  }
}

__global__ void k_route(const int* __restrict__ toke, const float2* __restrict__ tg,
                        int* __restrict__ counts, int* __restrict__ tokl,
                        float* __restrict__ gatel) {
  __shared__ int lcnt[NEXP];
  __shared__ int lbase[NEXP];
  const int tid = threadIdx.x;
  if (tid < NEXP) lcnt[tid] = 0;
  __syncthreads();
  const int t = blockIdx.x * 256 + tid;
  const int pe = toke[t];
  const int e0 = pe & 0xff, e1 = pe >> 8;
  const float2 g = tg[t];
  const int r0 = atomicAdd(&lcnt[e0], 1);
  const int r1 = atomicAdd(&lcnt[e1], 1);
  __syncthreads();
  if (tid < NEXP) lbase[tid] = atomicAdd(counts + tid, lcnt[tid]);
  __syncthreads();
  int i0 = lbase[e0] + r0;
  tokl[e0 * TOKENS + i0]  = (t << 1);
  gatel[e0 * TOKENS + i0] = g.x;
  int i1 = lbase[e1] + r1;
  tokl[e1 * TOKENS + i1]  = (t << 1) | 1;
  gatel[e1 * TOKENS + i1] = g.y;
}

// section offsets: pad to 256 (BM=256 tiles)
__global__ void k_soff(const int* __restrict__ cnts, int* __restrict__ soff, int* __restrict__ spc) {
  if (threadIdx.x == 0) {
    soff[8] = 0; spc[8] = TOKENS;
    int off = TOKENS;
    for (int e = 0; e < 8; e++) {
      int c = cnts[e];
      int p = (c + 255) & ~255;
      soff[e] = off; spc[e] = p;
      off += p;
    }
  }
}

__global__ void k_fill(const int* __restrict__ cnts, const int* __restrict__ soff,
                       const int* __restrict__ spc,
                       const int* __restrict__ tokl, const float* __restrict__ gatel,
                       const float* __restrict__ omega,
                       int* __restrict__ rmeta, float* __restrict__ rgate) {
  int r = blockIdx.x * 256 + threadIdx.x;
  if (r >= TROWS) return;
  if (r < TOKENS) { rmeta[r] = (r << 2) | 2; rgate[r] = omega[r]; return; }
  int meta = 3; float g = 0.f;
#pragma unroll
  for (int e = 0; e < 8; e++) {
    int off = soff[e];
    if (r >= off && r < off + spc[e]) {
      int i = r - off;
      if (i < cnts[e]) {
        int en = tokl[e * TOKENS + i];
        meta = ((en >> 1) << 2) | (en & 1);
        g = gatel[e * TOKENS + i];
      }
      break;
    }
  }
  rmeta[r] = meta; rgate[r] = g;
}

// gather X rows (f32 -> bf16) into k-slab layout xgp[s][row][32]
__global__ void k_gather(const float* __restrict__ x, const int* __restrict__ rmeta,
                         bf16_t* __restrict__ xgp) {
  int rbase = blockIdx.x * 128;
  for (int it = 0; it < 8; it++) {
    int id = it * 256 + threadIdx.x;
    int row = rbase + (id >> 4), s = id & 15;
    int meta = rmeta[row];
    union { bf16_t h[32]; uint4 u[4]; } t;
    if ((meta & 3) == 3) {
#pragma unroll
      for (int j = 0; j < 4; j++) t.u[j] = uint4{0, 0, 0, 0};
    } else {
      const float* src = x + (size_t)(meta >> 2) * D_MODEL + s * 32;
#pragma unroll
      for (int j = 0; j < 32; j += 4) {
        float4 v = *(const float4*)(src + j);
        t.h[j] = (bf16_t)v.x; t.h[j + 1] = (bf16_t)v.y;
        t.h[j + 2] = (bf16_t)v.z; t.h[j + 3] = (bf16_t)v.w;
      }
    }
    char* dst = (char*)xgp + ((size_t)s * TROWS + row) * 64;
#pragma unroll
    for (int j = 0; j < 4; j++) ((uint4*)dst)[j] = t.u[j];
  }
}

// ============================================================================
// 256x256 / BK=64 / 8-wave / 128-KiB-LDS 8-phase GEMM (T2+T3+T4+T5).
//
// LDS per buffer (2 buffers of 64 KiB, alternating per K-tile):
//   A: [ks][256 rows][64 B]  at  buf*65536 + ks*16384
//   B: [ks][256 cols][64 B]  at  buf*65536 + 32768 + ks*16384
// XOR swizzle: 16-B slot ^= (row>>1)&3 — inverse-swizzled per-lane GLOBAL
// source (global_load_lds dest must stay linear) + swizzled ds_read addr.
// Phases per K-tile: {F0@ks0, F1@ks0, F0@ks1, F1@ks1}; each phase frees one
// 16-KB region, each phase stages exactly one 16-KB region (2 loads/thread):
//   p0: A.ks1(kt+1)  p1: B.ks1(kt+1)  p2: A.ks0(kt+2)  p3: B.ks0(kt+2)
// vmcnt(4) once per K-tile at p3 (counted, never 0 in steady state).
// MFMA operands SWAPPED (mfma(B,A)) so lane holds row=l16, cols=quad*4+i..+3
// -> packed 8-B/16-B epilogue stores, no LDS transpose.
// ============================================================================
template <int KT, int NB, int EPI>
__global__ __launch_bounds__(512, 2) void k_gemm256(
    const bf16_t* __restrict__ Ab, const bf16_t* __restrict__ wEx,
    const bf16_t* __restrict__ wUn, const float* __restrict__ bEx,
    const float* __restrict__ bUn,
    const int* __restrict__ soff, const int* __restrict__ spc,
    bf16_t* __restrict__ hpOut,
    const int* __restrict__ rmeta, const float* __restrict__ rgate,
    bf16_t* __restrict__ s0, bf16_t* __restrict__ s1, float* __restrict__ outF) {
  const int sec = blockIdx.z, mt = blockIdx.x, nt = blockIdx.y;
  if (mt * 256 >= spc[sec]) return;
  const int groff = soff[sec];
  const char* Bsec = (const char*)((sec == 8) ? wUn : (wEx + (size_t)sec * (2 * KT) * NB * 32));
  const float* bias = (sec == 8) ? bUn : (bEx + sec * NB);

  __shared__ char smem[131072];
  const int tid = threadIdx.x;
  const int wave = tid >> 6, lane = tid & 63;
  const int l16 = lane & 15, quad = lane >> 4;
  const int wm = wave >> 2, wn = wave & 3;

  // staging: thread covers chunks c = tid, tid+512 of each 16-KB region
  // chunk c -> LDS (row=c>>2, slot=c&3); source slot = slot ^ ((row>>1)&3)
  const int r0 = tid >> 2;
  const int ss = (tid & 3) ^ ((tid >> 3) & 3);
  const int grow0 = groff + mt * 256;
  const char* aSrc = (const char*)Ab + (size_t)(grow0 + r0) * 64 + ss * 16;
  const char* bSrc = Bsec + (size_t)(nt * 256 + r0) * 64 + ss * 16;
  char* ldsW = smem + wave * 1024;

  // fragment read offsets (swizzled)
  const int swz = ((quad ^ ((l16 >> 1) & 3)) << 4);
  const int aRd = (wm * 128 + l16) * 64 + swz;
  const int bRd = 32768 + (wn * 64 + l16) * 64 + swz;

  f32x4_t acc[8][4];
#pragma unroll
  for (int m = 0; m < 8; m++)
#pragma unroll
    for (int n = 0; n < 4; n++) acc[m][n] = f32x4_t{0.f, 0.f, 0.f, 0.f};

  bf16x8_t Ar[4], Br[4];

  auto stageA = [&](int kt, int ks) {
    const char* g = aSrc + (size_t)(2 * kt + ks) * ((size_t)TROWS * 64);
    char* l = ldsW + (kt & 1) * 65536 + ks * 16384;
    load_lds16(g, l);
    load_lds16(g + 8192, l + 8192);
  };
  auto stageB = [&](int kt, int ks) {
    const char* g = bSrc + (size_t)(2 * kt + ks) * ((size_t)NB * 64);
    char* l = ldsW + (kt & 1) * 65536 + 32768 + ks * 16384;
    load_lds16(g, l);
    load_lds16(g + 8192, l + 8192);
  };
  auto ldA = [&](int buf, int ks, int fmB) {
    const char* p = smem + buf * 65536 + ks * 16384 + aRd + fmB * 1024;
#pragma unroll
    for (int k = 0; k < 4; k++) Ar[k] = *(const bf16x8_t*)(p + k * 1024);
  };
  auto ldB = [&](int buf, int ks) {
    const char* p = smem + buf * 65536 + ks * 16384 + bRd;
#pragma unroll
    for (int k = 0; k < 4; k++) Br[k] = *(const bf16x8_t*)(p + k * 1024);
  };
  auto mfma8 = [&](int fmB) {
    __builtin_amdgcn_s_setprio(1);
#pragma unroll
    for (int m = 0; m < 4; m++)
#pragma unroll
      for (int n = 0; n < 4; n++)
        acc[fmB + m][n] = mfma_bf16(Br[n], Ar[m], acc[fmB + m][n]);  // swapped
    __builtin_amdgcn_s_setprio(0);
  };

  auto do_kt = [&](int kt, bool st01, bool st23, int vm) {
    const int buf = kt & 1;
    // phase 0: F0 @ ks0
    ldA(buf, 0, 0); ldB(buf, 0);
    if (st01) stageA(kt + 1, 1);
    __builtin_amdgcn_s_barrier();
    asm volatile("s_waitcnt lgkmcnt(0)" ::: "memory");
    __builtin_amdgcn_sched_barrier(0);
    mfma8(0);
    __builtin_amdgcn_s_barrier();
    // phase 1: F1 @ ks0
    ldA(buf, 0, 4);
    if (st01) stageB(kt + 1, 1);
    __builtin_amdgcn_s_barrier();
    asm volatile("s_waitcnt lgkmcnt(0)" ::: "memory");
    __builtin_amdgcn_sched_barrier(0);
    mfma8(4);
    __builtin_amdgcn_s_barrier();
    // phase 2: F0 @ ks1
    ldA(buf, 1, 0); ldB(buf, 1);
    if (st23) stageA(kt + 2, 0);
    __builtin_amdgcn_s_barrier();
    asm volatile("s_waitcnt lgkmcnt(0)" ::: "memory");
    __builtin_amdgcn_sched_barrier(0);
    mfma8(0);
    __builtin_amdgcn_s_barrier();
    // phase 3: F1 @ ks1  (+ once-per-K-tile counted vmcnt)
    ldA(buf, 1, 4);
    if (st23) stageB(kt + 2, 0);
    if (vm == 4)      asm volatile("s_waitcnt vmcnt(4)" ::: "memory");
    else if (vm == 0) asm volatile("s_waitcnt vmcnt(0)" ::: "memory");
    __builtin_amdgcn_s_barrier();
    asm volatile("s_waitcnt lgkmcnt(0)" ::: "memory");
    __builtin_amdgcn_sched_barrier(0);
    mfma8(4);
    __builtin_amdgcn_s_barrier();
  };

  // prologue: kt0 fully + kt1.ks0 (12 loads); wait kt0 landed (4 in flight)
  stageA(0, 0); stageB(0, 0); stageA(0, 1); stageB(0, 1);
  stageA(1, 0); stageB(1, 0);
  asm volatile("s_waitcnt vmcnt(4)" ::: "memory");
  __builtin_amdgcn_s_barrier();

#pragma unroll 2
  for (int kt = 0; kt < KT - 2; ++kt) do_kt(kt, true, true, 4);
  do_kt(KT - 2, true, false, 0);
  do_kt(KT - 1, false, false, -1);

  // ---- epilogue: lane holds C[row = wm*128+m*16+l16][col = nt*256+wn*64+n*16+quad*4 .. +3]
  const int colq = wn * 64 + quad * 4;
  float4 bv[4];
#pragma unroll
  for (int n = 0; n < 4; n++)
    bv[n] = *(const float4*)(bias + nt * 256 + colq + n * 16);

  if constexpr (EPI == 0) {
    // bias + gelu -> hp k-slab [slab][TROWS][32], packed 8-B stores
#pragma unroll
    for (int m = 0; m < 8; m++) {
      const int row = grow0 + wm * 128 + m * 16 + l16;
#pragma unroll
      for (int n = 0; n < 4; n++) {
        float b4[4] = {bv[n].x, bv[n].y, bv[n].z, bv[n].w};
        union { bf16_t h[4]; uint2 u; } t;
#pragma unroll
        for (int i = 0; i < 4; i++)
          t.h[i] = (bf16_t)fast_gelu(acc[m][n][i] + b4[i]);
        char* dst = (char*)hpOut +
            ((size_t)(nt * 8 + wn * 2 + (n >> 1)) * TROWS + row) * 64 +
            (n & 1) * 32 + quad * 8;
        *(uint2*)dst = t.u;
      }
    }
  } else {
    // +b2, *gate, scatter by slot
#pragma unroll
    for (int m = 0; m < 8; m++) {
      const int grow = grow0 + wm * 128 + m * 16 + l16;
      const int dbase = nt * 256 + colq;
      if (sec == 8) {
        const float g = rgate[grow];
        float* dst = outF + (size_t)grow * D_MODEL + dbase;
#pragma unroll
        for (int n = 0; n < 4; n++) {
          float b4[4] = {bv[n].x, bv[n].y, bv[n].z, bv[n].w};
          float4 o;
          o.x = (acc[m][n][0] + b4[0]) * g;
          o.y = (acc[m][n][1] + b4[1]) * g;
          o.z = (acc[m][n][2] + b4[2]) * g;
          o.w = (acc[m][n][3] + b4[3]) * g;
          *(float4*)(dst + n * 16) = o;
        }
      } else {
        const int meta = rmeta[grow];
        const int slot = meta & 3;
        if (slot == 3) continue;
        const float g = rgate[grow];
        bf16_t* dst = (slot ? s1 : s0) + (size_t)(meta >> 2) * D_MODEL + dbase;
#pragma unroll
        for (int n = 0; n < 4; n++) {
          float b4[4] = {bv[n].x, bv[n].y, bv[n].z, bv[n].w};
          union { bf16_t h[4]; uint2 u; } t;
#pragma unroll
          for (int i = 0; i < 4; i++)
            t.h[i] = (bf16_t)((acc[m][n][i] + b4[i]) * g);
          *(uint2*)(dst + n * 16) = t.u;
        }
      }
    }
  }
}

__global__ void k_combine(const bf16x4_t* __restrict__ s0, const bf16x4_t* __restrict__ s1,
                          float4* __restrict__ out, int n4) {
  int i = blockIdx.x * blockDim.x + threadIdx.x;
  if (i >= n4) return;
  bf16x4_t a = s0[i], b = s1[i];
  float4 o = out[i];
  o.x += (float)a[0] + (float)b[0];
  o.y += (float)a[1] + (float)b[1];
  o.z += (float)a[2] + (float)b[2];
  o.w += (float)a[3] + (float)b[3];
  out[i] = o;
}

extern "C" void kernel_launch(void* const* d_in, const int* in_sizes, int n_in,
                              void* d_out, int out_size, void* d_ws, size_t ws_size,
                              hipStream_t stream) {
  (void)in_sizes; (void)n_in; (void)out_size; (void)ws_size;
  const float* x        = (const float*)d_in[0];
  const int*   task_ids = (const int*)  d_in[1];
  const float* task_emb = (const float*)d_in[2];
  const float* gate_w   = (const float*)d_in[3];
  const float* gate_b   = (const float*)d_in[4];
  const float* w1       = (const float*)d_in[5];
  const float* b1       = (const float*)d_in[6];
  const float* w2       = (const float*)d_in[7];
  const float* b2       = (const float*)d_in[8];
  const float* uw1      = (const float*)d_in[9];
  const float* ub1      = (const float*)d_in[10];
  const float* uw2      = (const float*)d_in[11];
  const float* ub2      = (const float*)d_in[12];

  char* ws = (char*)d_ws;
  bf16_t* w1p   = (bf16_t*)(ws + W1P_OFF);
  bf16_t* uw1p  = (bf16_t*)(ws + UW1P_OFF);
  bf16_t* w2p   = (bf16_t*)(ws + W2P_OFF);
  bf16_t* uw2p  = (bf16_t*)(ws + UW2P_OFF);
  bf16_t* s0    = (bf16_t*)(ws + S0_OFF);
  bf16_t* s1    = (bf16_t*)(ws + S1_OFF);
  int*    cnts  = (int*)   (ws + CNT_OFF);
  int*    tokl  = (int*)   (ws + TOKL_OFF);
  float*  gatel = (float*) (ws + GATEL_OFF);
  float*  omg   = (float*) (ws + OMEGA_OFF);
  double* tlog  = (double*)(ws + TLOG_OFF);
  int*    soff  = (int*)   (ws + SOFF_OFF);
  int*    spc   = (int*)   (ws + SPC_OFF);
  int*    rmeta = (int*)   (ws + RMETA_OFF);
  float*  rgate = (float*) (ws + RGATE_OFF);
  bf16_t* xgp   = (bf16_t*)(ws + XGP_OFF);
  bf16_t* hp    = (bf16_t*)(ws + HP_OFF);
  int*    toke  = (int*)   (ws + TOKE_OFF);
  float2* tg    = (float2*)(ws + TG_OFF);

  float* out    = (float*)d_out;
  float* logits = out + (size_t)TOKENS * D_MODEL;

  hipMemsetAsync(cnts, 0, 64, stream);

  k_pack<<<dim3(32, 8, NEXP), 256, 0, stream>>>(w1, w1p, D_MODEL, D_FF);
  k_pack<<<dim3(8, 32, NEXP), 256, 0, stream>>>(w2, w2p, D_FF, D_MODEL);
  k_pack<<<dim3(32, 8, 1),    256, 0, stream>>>(uw1, uw1p, D_MODEL, D_FF);
  k_pack<<<dim3(8, 32, 1),    256, 0, stream>>>(uw2, uw2p, D_FF, D_MODEL);
  k_tlog<<<1, 64, 0, stream>>>(task_ids, task_emb, gate_w, gate_b, tlog);
  k_gate<<<dim3(TOKENS / 4), 256, 0, stream>>>(x, gate_w, tlog, logits, toke, tg, omg);
  k_route<<<dim3(TOKENS / 256), 256, 0, stream>>>(toke, tg, cnts, tokl, gatel);
  k_soff<<<1, 64, 0, stream>>>(cnts, soff, spc);
  k_fill<<<dim3((TROWS + 255) / 256), 256, 0, stream>>>(cnts, soff, spc, tokl, gatel, omg,
                                                        rmeta, rgate);
  k_gather<<<dim3(TROWS / 128), 256, 0, stream>>>(x, rmeta, xgp);
  k_gemm256<8, D_FF, 0><<<dim3(32, 8, 9), 512, 0, stream>>>(
      xgp, w1p, uw1p, b1, ub1, soff, spc, hp,
      nullptr, nullptr, nullptr, nullptr, nullptr);
  k_gemm256<32, D_MODEL, 1><<<dim3(32, 2, 9), 512, 0, stream>>>(
      hp, w2p, uw2p, b2, ub2, soff, spc, nullptr,
      rmeta, rgate, s0, s1, out);
  const int n4 = TOKENS * D_MODEL / 4;
  k_combine<<<dim3(n4 / 256), 256, 0, stream>>>((const bf16x4_t*)s0, (const bf16x4_t*)s1,
                                                (float4*)out, n4);
}

// Round 2
// 460.558 us; speedup vs baseline: 1.2510x; 1.2510x over previous
//
#include <hip/hip_runtime.h>

#define D_MODEL 512
#define D_FF    2048
#define NEXP    8
#define TOKENS  8192
#define TROWS   26368     // 8192 universal + <=18176 expert slots padded to 256

typedef __bf16 bf16_t;
typedef __attribute__((ext_vector_type(8))) __bf16 bf16x8_t;
typedef __attribute__((ext_vector_type(4))) __bf16 bf16x4_t;
typedef __attribute__((ext_vector_type(4))) float  f32x4_t;

// ---- workspace layout (bytes) ----
#define W1P_OFF    0u            // bf16 [8][16][2048][32]
#define UW1P_OFF   16777216u     // bf16 [16][2048][32]
#define W2P_OFF    18874368u     // bf16 [8][64][512][32]
#define UW2P_OFF   35651584u     // bf16 [64][512][32]
#define CNT_OFF    37748736u     // int[16]
#define TOKL_OFF   37748800u     // int  [8][8192]
#define GATEL_OFF  38010944u     // float[8][8192]
#define OMEGA_OFF  38273088u     // float[8192]
#define TLOG_OFF   38305856u     // double[8][8]
#define SOFF_OFF   38306368u     // int[16]
#define SPC_OFF    38306432u     // int[16]
#define RMETA_OFF  38306496u     // int[TROWS]
#define RGATE_OFF  38411968u     // float[TROWS]
#define XGP_OFF    38517440u     // bf16 [16][TROWS][32]  (26,999,808 B)
#define S0_OFF     38517440u     // ALIAS of XGP (xgp dead before gemm2 writes s0/s1)
#define S1_OFF     46906048u     // ALIAS of XGP
#define HP_OFF     65517248u     // bf16 [64][TROWS][32]  (107,999,232 B)
#define TOKE_OFF   173516480u    // int[8192]
#define TG_OFF     173549248u    // float2[8192]

__device__ inline f32x4_t mfma_bf16(bf16x8_t a, bf16x8_t b, f32x4_t c) {
  return __builtin_amdgcn_mfma_f32_16x16x32_bf16(a, b, c, 0, 0, 0);
}

__device__ __forceinline__ void load_lds16(const void* g, void* l) {
  __builtin_amdgcn_global_load_lds(
      (const __attribute__((address_space(1))) unsigned int*)g,
      (__attribute__((address_space(3))) unsigned int*)l, 16, 0, 0);
}

// fast gelu: max abs err ~3e-4 << bf16 quantum
__device__ __forceinline__ float fast_gelu(float x) {
  float z = 0.7978845608f * (x + 0.044715f * x * x * x);
  float u = __expf(2.0f * z);
  float th = (u - 1.0f) * __builtin_amdgcn_rcpf(u + 1.0f);
  return 0.5f * x * (1.0f + th);
}

// pack in[R][C] f32 -> out[R/32][C][32] bf16
__global__ void k_pack(const float* __restrict__ in, bf16_t* __restrict__ out, int R, int C) {
  __shared__ float tile[64][65];
  const size_t mat = (size_t)blockIdx.z * R * C;
  in  += mat;
  out += mat;
  int r0 = blockIdx.y * 64, c0 = blockIdx.x * 64;
  for (int i = threadIdx.x; i < 4096; i += 256) {
    int r = i >> 6, c = i & 63;
    tile[r][c] = in[(size_t)(r0 + r) * C + c0 + c];
  }
  __syncthreads();
  int item = threadIdx.x >> 1, jh = threadIdx.x & 1;
  int c = item & 63, s = item >> 6;
  union { bf16_t h[16]; uint4 u[2]; } t;
#pragma unroll
  for (int k = 0; k < 16; k++) t.h[k] = (bf16_t)tile[s * 32 + jh * 16 + k][c];
  char* dst = (char*)out + ((size_t)((r0 >> 5) + s) * C + (c0 + c)) * 64 + jh * 32;
  ((uint4*)dst)[0] = t.u[0];
  ((uint4*)dst)[1] = t.u[1];
}

__global__ void k_tlog(const int* __restrict__ task_ids, const float* __restrict__ task_emb,
                       const float* __restrict__ gate_w, const float* __restrict__ gate_b,
                       double* __restrict__ tlog) {
  int i = threadIdx.x;
  if (i >= 64) return;
  int b = i >> 3, e = i & 7;
  const float* te = task_emb + (size_t)task_ids[b] * D_MODEL;
  double acc = (double)gate_b[e];
  for (int d = 0; d < D_MODEL; d++)
    acc += (double)te[d] * (double)gate_w[(size_t)(D_MODEL + d) * NEXP + e];
  tlog[i] = acc;
}

// one wave per token: f64 logits, top-2 softmax
__global__ void k_gate(const float* __restrict__ x, const float* __restrict__ gate_w,
                       const double* __restrict__ tlog,
                       float* __restrict__ logits_out,
                       int* __restrict__ toke, float2* __restrict__ tg,
                       float* __restrict__ omega) {
  int gtid = blockIdx.x * blockDim.x + threadIdx.x;
  int t = gtid >> 6;
  int lane = gtid & 63;
  if (t >= TOKENS) return;
  const float* xr = x + (size_t)t * D_MODEL;
  int d0 = lane * 8;
  float4 xa = *(const float4*)(xr + d0);
  float4 xc = *(const float4*)(xr + d0 + 4);
  float xv[8] = {xa.x, xa.y, xa.z, xa.w, xc.x, xc.y, xc.z, xc.w};
  double acc[NEXP];
#pragma unroll
  for (int e = 0; e < NEXP; e++) acc[e] = 0.0;
#pragma unroll
  for (int j = 0; j < 8; j++) {
    const float* gwr = gate_w + (size_t)(d0 + j) * NEXP;
    float4 g0 = *(const float4*)gwr;
    float4 g1 = *(const float4*)(gwr + 4);
    double xd = (double)xv[j];
    acc[0] += xd * (double)g0.x; acc[1] += xd * (double)g0.y;
    acc[2] += xd * (double)g0.z; acc[3] += xd * (double)g0.w;
    acc[4] += xd * (double)g1.x; acc[5] += xd * (double)g1.y;
    acc[6] += xd * (double)g1.z; acc[7] += xd * (double)g1.w;
  }
#pragma unroll
  for (int off = 32; off > 0; off >>= 1) {
#pragma unroll
    for (int e = 0; e < NEXP; e++) acc[e] += __shfl_xor(acc[e], off);
  }
  if (lane == 0) {
    int b = t >> 10;
    double lg[NEXP];
#pragma unroll
    for (int e = 0; e < NEXP; e++) {
      lg[e] = acc[e] + tlog[b * NEXP + e];
      logits_out[(size_t)t * NEXP + e] = (float)lg[e];
    }
    int e0 = 0;
    for (int e = 1; e < NEXP; e++) if (lg[e] > lg[e0]) e0 = e;
    int e1 = (e0 == 0) ? 1 : 0;
    for (int e = 0; e < NEXP; e++) if (e != e0 && lg[e] > lg[e1]) e1 = e;
    double p0 = 1.0 / (1.0 + exp(lg[e1] - lg[e0]));
    float g0f = (float)p0;
    float g1f = (float)(1.0 - p0);
    omega[t] = 1.0f - g0f;
    toke[t] = e0 | (e1 << 8);
    tg[t] = float2{g0f, g1f};
  }
}

__global__ void k_route(const int* __restrict__ toke, const float2* __restrict__ tg,
                        int* __restrict__ counts, int* __restrict__ tokl,
                        float* __restrict__ gatel) {
  __shared__ int lcnt[NEXP];
  __shared__ int lbase[NEXP];
  const int tid = threadIdx.x;
  if (tid < NEXP) lcnt[tid] = 0;
  __syncthreads();
  const int t = blockIdx.x * 256 + tid;
  const int pe = toke[t];
  const int e0 = pe & 0xff, e1 = pe >> 8;
  const float2 g = tg[t];
  const int r0 = atomicAdd(&lcnt[e0], 1);
  const int r1 = atomicAdd(&lcnt[e1], 1);
  __syncthreads();
  if (tid < NEXP) lbase[tid] = atomicAdd(counts + tid, lcnt[tid]);
  __syncthreads();
  int i0 = lbase[e0] + r0;
  tokl[e0 * TOKENS + i0]  = (t << 1);
  gatel[e0 * TOKENS + i0] = g.x;
  int i1 = lbase[e1] + r1;
  tokl[e1 * TOKENS + i1]  = (t << 1) | 1;
  gatel[e1 * TOKENS + i1] = g.y;
}

// section offsets: pad to 256 (BM=256 tiles)
__global__ void k_soff(const int* __restrict__ cnts, int* __restrict__ soff, int* __restrict__ spc) {
  if (threadIdx.x == 0) {
    soff[8] = 0; spc[8] = TOKENS;
    int off = TOKENS;
    for (int e = 0; e < 8; e++) {
      int c = cnts[e];
      int p = (c + 255) & ~255;
      soff[e] = off; spc[e] = p;
      off += p;
    }
  }
}

__global__ void k_fill(const int* __restrict__ cnts, const int* __restrict__ soff,
                       const int* __restrict__ spc,
                       const int* __restrict__ tokl, const float* __restrict__ gatel,
                       const float* __restrict__ omega,
                       int* __restrict__ rmeta, float* __restrict__ rgate) {
  int r = blockIdx.x * 256 + threadIdx.x;
  if (r >= TROWS) return;
  if (r < TOKENS) { rmeta[r] = (r << 2) | 2; rgate[r] = omega[r]; return; }
  int meta = 3; float g = 0.f;
#pragma unroll
  for (int e = 0; e < 8; e++) {
    int off = soff[e];
    if (r >= off && r < off + spc[e]) {
      int i = r - off;
      if (i < cnts[e]) {
        int en = tokl[e * TOKENS + i];
        meta = ((en >> 1) << 2) | (en & 1);
        g = gatel[e * TOKENS + i];
      }
      break;
    }
  }
  rmeta[r] = meta; rgate[r] = g;
}

// gather X rows (f32 -> bf16) into k-slab layout xgp[s][row][32]
__global__ void k_gather(const float* __restrict__ x, const int* __restrict__ rmeta,
                         bf16_t* __restrict__ xgp) {
  int rbase = blockIdx.x * 128;
  for (int it = 0; it < 8; it++) {
    int id = it * 256 + threadIdx.x;
    int row = rbase + (id >> 4), s = id & 15;
    int meta = rmeta[row];
    union { bf16_t h[32]; uint4 u[4]; } t;
    if ((meta & 3) == 3) {
#pragma unroll
      for (int j = 0; j < 4; j++) t.u[j] = uint4{0, 0, 0, 0};
    } else {
      const float* src = x + (size_t)(meta >> 2) * D_MODEL + s * 32;
#pragma unroll
      for (int j = 0; j < 32; j += 4) {
        float4 v = *(const float4*)(src + j);
        t.h[j] = (bf16_t)v.x; t.h[j + 1] = (bf16_t)v.y;
        t.h[j + 2] = (bf16_t)v.z; t.h[j + 3] = (bf16_t)v.w;
      }
    }
    char* dst = (char*)xgp + ((size_t)s * TROWS + row) * 64;
#pragma unroll
    for (int j = 0; j < 4; j++) ((uint4*)dst)[j] = t.u[j];
  }
}

// ============================================================================
// 256x256 / BK=64 / 8-wave / 128-KiB-LDS 8-phase GEMM (T2+T3+T4+T5)
// + XCD-supergroup dispatch (T1):
//   supergroup = NT nt-tiles x 4 mt-tiles (S = 4*NT blocks), placed entirely
//   on one XCD so the NT concurrent sharers of each A-panel and 4 sharers of
//   each B-panel hit that XCD's L2 instead of going cross-XCD to L3.
//   Per-XCD row rotation sg = 8k + ((xcd+k)&7): every XCD visits each section
//   exactly once, and each experts' active (low-mt) supergroups rotate across
//   XCDs -> each XCD gets ~1 universal + 2 expert-active supergroups.
// ============================================================================
template <int KT, int NB, int EPI, int NT>
__global__ __launch_bounds__(512, 2) void k_gemm256(
    const bf16_t* __restrict__ Ab, const bf16_t* __restrict__ wEx,
    const bf16_t* __restrict__ wUn, const float* __restrict__ bEx,
    const float* __restrict__ bUn,
    const int* __restrict__ soff, const int* __restrict__ spc,
    bf16_t* __restrict__ hpOut,
    const int* __restrict__ rmeta, const float* __restrict__ rgate,
    bf16_t* __restrict__ s0, bf16_t* __restrict__ s1, float* __restrict__ outF) {
  constexpr int S = 4 * NT;          // blocks per supergroup (32 or 8)
  const int wg  = blockIdx.x;
  const int xcd = wg & 7;
  const int j   = wg >> 3;
  const int k   = j / S;             // per-XCD supergroup row (0..8)
  const int m   = j % S;
  const int sg  = 8 * k + ((xcd + k) & 7);
  const int flat = sg * S + m;
  const int nt  = flat % NT;
  const int mt  = (flat / NT) & 31;
  const int sec = flat / (NT * 32);

  if (mt * 256 >= spc[sec]) return;
  const int groff = soff[sec];
  const char* Bsec = (const char*)((sec == 8) ? wUn : (wEx + (size_t)sec * (2 * KT) * NB * 32));
  const float* bias = (sec == 8) ? bUn : (bEx + sec * NB);

  __shared__ char smem[131072];
  const int tid = threadIdx.x;
  const int wave = tid >> 6, lane = tid & 63;
  const int l16 = lane & 15, quad = lane >> 4;
  const int wm = wave >> 2, wn = wave & 3;

  // staging: thread covers chunks c = tid, tid+512 of each 16-KB region
  // chunk c -> LDS (row=c>>2, slot=c&3); source slot = slot ^ ((row>>1)&3)
  const int r0 = tid >> 2;
  const int ss = (tid & 3) ^ ((tid >> 3) & 3);
  const int grow0 = groff + mt * 256;
  const char* aSrc = (const char*)Ab + (size_t)(grow0 + r0) * 64 + ss * 16;
  const char* bSrc = Bsec + (size_t)(nt * 256 + r0) * 64 + ss * 16;
  char* ldsW = smem + wave * 1024;

  // fragment read offsets (swizzled)
  const int swz = ((quad ^ ((l16 >> 1) & 3)) << 4);
  const int aRd = (wm * 128 + l16) * 64 + swz;
  const int bRd = 32768 + (wn * 64 + l16) * 64 + swz;

  f32x4_t acc[8][4];
#pragma unroll
  for (int i = 0; i < 8; i++)
#pragma unroll
    for (int n = 0; n < 4; n++) acc[i][n] = f32x4_t{0.f, 0.f, 0.f, 0.f};

  bf16x8_t Ar[4], Br[4];

  auto stageA = [&](int kt, int ks) {
    const char* g = aSrc + (size_t)(2 * kt + ks) * ((size_t)TROWS * 64);
    char* l = ldsW + (kt & 1) * 65536 + ks * 16384;
    load_lds16(g, l);
    load_lds16(g + 8192, l + 8192);
  };
  auto stageB = [&](int kt, int ks) {
    const char* g = bSrc + (size_t)(2 * kt + ks) * ((size_t)NB * 64);
    char* l = ldsW + (kt & 1) * 65536 + 32768 + ks * 16384;
    load_lds16(g, l);
    load_lds16(g + 8192, l + 8192);
  };
  auto ldA = [&](int buf, int ks, int fmB) {
    const char* p = smem + buf * 65536 + ks * 16384 + aRd + fmB * 1024;
#pragma unroll
    for (int kk = 0; kk < 4; kk++) Ar[kk] = *(const bf16x8_t*)(p + kk * 1024);
  };
  auto ldB = [&](int buf, int ks) {
    const char* p = smem + buf * 65536 + ks * 16384 + bRd;
#pragma unroll
    for (int kk = 0; kk < 4; kk++) Br[kk] = *(const bf16x8_t*)(p + kk * 1024);
  };
  auto mfma8 = [&](int fmB) {
    __builtin_amdgcn_s_setprio(1);
#pragma unroll
    for (int mm = 0; mm < 4; mm++)
#pragma unroll
      for (int n = 0; n < 4; n++)
        acc[fmB + mm][n] = mfma_bf16(Br[n], Ar[mm], acc[fmB + mm][n]);  // swapped
    __builtin_amdgcn_s_setprio(0);
  };

  auto do_kt = [&](int kt, bool st01, bool st23, int vm) {
    const int buf = kt & 1;
    // phase 0: F0 @ ks0
    ldA(buf, 0, 0); ldB(buf, 0);
    if (st01) stageA(kt + 1, 1);
    __builtin_amdgcn_s_barrier();
    asm volatile("s_waitcnt lgkmcnt(0)" ::: "memory");
    __builtin_amdgcn_sched_barrier(0);
    mfma8(0);
    __builtin_amdgcn_s_barrier();
    // phase 1: F1 @ ks0
    ldA(buf, 0, 4);
    if (st01) stageB(kt + 1, 1);
    __builtin_amdgcn_s_barrier();
    asm volatile("s_waitcnt lgkmcnt(0)" ::: "memory");
    __builtin_amdgcn_sched_barrier(0);
    mfma8(4);
    __builtin_amdgcn_s_barrier();
    // phase 2: F0 @ ks1
    ldA(buf, 1, 0); ldB(buf, 1);
    if (st23) stageA(kt + 2, 0);
    __builtin_amdgcn_s_barrier();
    asm volatile("s_waitcnt lgkmcnt(0)" ::: "memory");
    __builtin_amdgcn_sched_barrier(0);
    mfma8(0);
    __builtin_amdgcn_s_barrier();
    // phase 3: F1 @ ks1  (+ once-per-K-tile counted vmcnt)
    ldA(buf, 1, 4);
    if (st23) stageB(kt + 2, 0);
    if (vm == 4)      asm volatile("s_waitcnt vmcnt(4)" ::: "memory");
    else if (vm == 0) asm volatile("s_waitcnt vmcnt(0)" ::: "memory");
    __builtin_amdgcn_s_barrier();
    asm volatile("s_waitcnt lgkmcnt(0)" ::: "memory");
    __builtin_amdgcn_sched_barrier(0);
    mfma8(4);
    __builtin_amdgcn_s_barrier();
  };

  // prologue: kt0 fully + kt1.ks0 (12 loads); wait kt0 landed (4 in flight)
  stageA(0, 0); stageB(0, 0); stageA(0, 1); stageB(0, 1);
  stageA(1, 0); stageB(1, 0);
  asm volatile("s_waitcnt vmcnt(4)" ::: "memory");
  __builtin_amdgcn_s_barrier();

#pragma unroll 2
  for (int kt = 0; kt < KT - 2; ++kt) do_kt(kt, true, true, 4);
  do_kt(KT - 2, true, false, 0);
  do_kt(KT - 1, false, false, -1);

  // ---- epilogue: lane holds C[row = wm*128+mm*16+l16][col = nt*256+wn*64+n*16+quad*4 .. +3]
  const int colq = wn * 64 + quad * 4;
  float4 bv[4];
#pragma unroll
  for (int n = 0; n < 4; n++)
    bv[n] = *(const float4*)(bias + nt * 256 + colq + n * 16);

  if constexpr (EPI == 0) {
    // bias + gelu -> hp k-slab [slab][TROWS][32], packed 8-B stores
#pragma unroll
    for (int mm = 0; mm < 8; mm++) {
      const int row = grow0 + wm * 128 + mm * 16 + l16;
#pragma unroll
      for (int n = 0; n < 4; n++) {
        float b4[4] = {bv[n].x, bv[n].y, bv[n].z, bv[n].w};
        union { bf16_t h[4]; uint2 u; } t;
#pragma unroll
        for (int i = 0; i < 4; i++)
          t.h[i] = (bf16_t)fast_gelu(acc[mm][n][i] + b4[i]);
        char* dst = (char*)hpOut +
            ((size_t)(nt * 8 + wn * 2 + (n >> 1)) * TROWS + row) * 64 +
            (n & 1) * 32 + quad * 8;
        *(uint2*)dst = t.u;
      }
    }
  } else {
    // +b2, *gate, scatter by slot
#pragma unroll
    for (int mm = 0; mm < 8; mm++) {
      const int grow = grow0 + wm * 128 + mm * 16 + l16;
      const int dbase = nt * 256 + colq;
      if (sec == 8) {
        const float g = rgate[grow];
        float* dst = outF + (size_t)grow * D_MODEL + dbase;
#pragma unroll
        for (int n = 0; n < 4; n++) {
          float b4[4] = {bv[n].x, bv[n].y, bv[n].z, bv[n].w};
          float4 o;
          o.x = (acc[mm][n][0] + b4[0]) * g;
          o.y = (acc[mm][n][1] + b4[1]) * g;
          o.z = (acc[mm][n][2] + b4[2]) * g;
          o.w = (acc[mm][n][3] + b4[3]) * g;
          *(float4*)(dst + n * 16) = o;
        }
      } else {
        const int meta = rmeta[grow];
        const int slot = meta & 3;
        if (slot == 3) continue;
        const float g = rgate[grow];
        bf16_t* dst = (slot ? s1 : s0) + (size_t)(meta >> 2) * D_MODEL + dbase;
#pragma unroll
        for (int n = 0; n < 4; n++) {
          float b4[4] = {bv[n].x, bv[n].y, bv[n].z, bv[n].w};
          union { bf16_t h[4]; uint2 u; } t;
#pragma unroll
          for (int i = 0; i < 4; i++)
            t.h[i] = (bf16_t)((acc[mm][n][i] + b4[i]) * g);
          *(uint2*)(dst + n * 16) = t.u;
        }
      }
    }
  }
}

__global__ void k_combine(const bf16x4_t* __restrict__ s0, const bf16x4_t* __restrict__ s1,
                          float4* __restrict__ out, int n4) {
  int i = blockIdx.x * blockDim.x + threadIdx.x;
  if (i >= n4) return;
  bf16x4_t a = s0[i], b = s1[i];
  float4 o = out[i];
  o.x += (float)a[0] + (float)b[0];
  o.y += (float)a[1] + (float)b[1];
  o.z += (float)a[2] + (float)b[2];
  o.w += (float)a[3] + (float)b[3];
  out[i] = o;
}

extern "C" void kernel_launch(void* const* d_in, const int* in_sizes, int n_in,
                              void* d_out, int out_size, void* d_ws, size_t ws_size,
                              hipStream_t stream) {
  (void)in_sizes; (void)n_in; (void)out_size; (void)ws_size;
  const float* x        = (const float*)d_in[0];
  const int*   task_ids = (const int*)  d_in[1];
  const float* task_emb = (const float*)d_in[2];
  const float* gate_w   = (const float*)d_in[3];
  const float* gate_b   = (const float*)d_in[4];
  const float* w1       = (const float*)d_in[5];
  const float* b1       = (const float*)d_in[6];
  const float* w2       = (const float*)d_in[7];
  const float* b2       = (const float*)d_in[8];
  const float* uw1      = (const float*)d_in[9];
  const float* ub1      = (const float*)d_in[10];
  const float* uw2      = (const float*)d_in[11];
  const float* ub2      = (const float*)d_in[12];

  char* ws = (char*)d_ws;
  bf16_t* w1p   = (bf16_t*)(ws + W1P_OFF);
  bf16_t* uw1p  = (bf16_t*)(ws + UW1P_OFF);
  bf16_t* w2p   = (bf16_t*)(ws + W2P_OFF);
  bf16_t* uw2p  = (bf16_t*)(ws + UW2P_OFF);
  bf16_t* s0    = (bf16_t*)(ws + S0_OFF);
  bf16_t* s1    = (bf16_t*)(ws + S1_OFF);
  int*    cnts  = (int*)   (ws + CNT_OFF);
  int*    tokl  = (int*)   (ws + TOKL_OFF);
  float*  gatel = (float*) (ws + GATEL_OFF);
  float*  omg   = (float*) (ws + OMEGA_OFF);
  double* tlog  = (double*)(ws + TLOG_OFF);
  int*    soff  = (int*)   (ws + SOFF_OFF);
  int*    spc   = (int*)   (ws + SPC_OFF);
  int*    rmeta = (int*)   (ws + RMETA_OFF);
  float*  rgate = (float*) (ws + RGATE_OFF);
  bf16_t* xgp   = (bf16_t*)(ws + XGP_OFF);
  bf16_t* hp    = (bf16_t*)(ws + HP_OFF);
  int*    toke  = (int*)   (ws + TOKE_OFF);
  float2* tg    = (float2*)(ws + TG_OFF);

  float* out    = (float*)d_out;
  float* logits = out + (size_t)TOKENS * D_MODEL;

  hipMemsetAsync(cnts, 0, 64, stream);

  k_pack<<<dim3(32, 8, NEXP), 256, 0, stream>>>(w1, w1p, D_MODEL, D_FF);
  k_pack<<<dim3(8, 32, NEXP), 256, 0, stream>>>(w2, w2p, D_FF, D_MODEL);
  k_pack<<<dim3(32, 8, 1),    256, 0, stream>>>(uw1, uw1p, D_MODEL, D_FF);
  k_pack<<<dim3(8, 32, 1),    256, 0, stream>>>(uw2, uw2p, D_FF, D_MODEL);
  k_tlog<<<1, 64, 0, stream>>>(task_ids, task_emb, gate_w, gate_b, tlog);
  k_gate<<<dim3(TOKENS / 4), 256, 0, stream>>>(x, gate_w, tlog, logits, toke, tg, omg);
  k_route<<<dim3(TOKENS / 256), 256, 0, stream>>>(toke, tg, cnts, tokl, gatel);
  k_soff<<<1, 64, 0, stream>>>(cnts, soff, spc);
  k_fill<<<dim3((TROWS + 255) / 256), 256, 0, stream>>>(cnts, soff, spc, tokl, gatel, omg,
                                                        rmeta, rgate);
  k_gather<<<dim3(TROWS / 128), 256, 0, stream>>>(x, rmeta, xgp);
  // 1-D grids: supergroup XCD swizzle handled in-kernel
  k_gemm256<8, D_FF, 0, 8><<<dim3(32 * 8 * 9), 512, 0, stream>>>(
      xgp, w1p, uw1p, b1, ub1, soff, spc, hp,
      nullptr, nullptr, nullptr, nullptr, nullptr);
  k_gemm256<32, D_MODEL, 1, 2><<<dim3(32 * 2 * 9), 512, 0, stream>>>(
      hp, w2p, uw2p, b2, ub2, soff, spc, nullptr,
      rmeta, rgate, s0, s1, out);
  const int n4 = TOKENS * D_MODEL / 4;
  k_combine<<<dim3(n4 / 256), 256, 0, stream>>>((const bf16x4_t*)s0, (const bf16x4_t*)s1,
                                                (float4*)out, n4);
}

// Round 3
// 402.719 us; speedup vs baseline: 1.4307x; 1.1436x over previous
//
#include <hip/hip_runtime.h>

#define D_MODEL 512
#define D_FF    2048
#define NEXP    8
#define TOKENS  8192
#define TROWS   26368     // 8192 universal + <=18176 expert slots padded to 256

typedef __bf16 bf16_t;
typedef __attribute__((ext_vector_type(8))) __bf16 bf16x8_t;
typedef __attribute__((ext_vector_type(4))) __bf16 bf16x4_t;
typedef __attribute__((ext_vector_type(4))) float  f32x4_t;

// ---- workspace layout (bytes) ----
#define W1P_OFF    0u            // bf16 [8][16][2048][32]
#define UW1P_OFF   16777216u     // bf16 [16][2048][32]
#define W2P_OFF    18874368u     // bf16 [8][64][512][32]
#define UW2P_OFF   35651584u     // bf16 [64][512][32]
#define CNT_OFF    37748736u     // int[16]
#define TOKL_OFF   37748800u     // int  [8][8192]
#define GATEL_OFF  38010944u     // float[8][8192]
#define OMEGA_OFF  38273088u     // float[8192]
#define TLOG_OFF   38305856u     // double[8][8]
#define SOFF_OFF   38306368u     // int[16]
#define SPC_OFF    38306432u     // int[16]
#define RMETA_OFF  38306496u     // int[TROWS]
#define RGATE_OFF  38411968u     // float[TROWS]
#define XGP_OFF    38517440u     // bf16 [16][TROWS][32]  (26,999,808 B)
#define S0_OFF     38517440u     // ALIAS of XGP (xgp dead before gemm2 writes s0/s1)
#define S1_OFF     46906048u     // ALIAS of XGP
#define HP_OFF     65517248u     // bf16 [64][TROWS][32]  (107,999,232 B)
#define TOKE_OFF   173516480u    // int[8192]
#define TG_OFF     173549248u    // float2[8192]
#define TMAP_OFF   173614784u    // int[136]: [0..127] tile map (sec<<8|mt), [128] ntiles

__device__ inline f32x4_t mfma_bf16(bf16x8_t a, bf16x8_t b, f32x4_t c) {
  return __builtin_amdgcn_mfma_f32_16x16x32_bf16(a, b, c, 0, 0, 0);
}

__device__ __forceinline__ void load_lds16(const void* g, void* l) {
  __builtin_amdgcn_global_load_lds(
      (const __attribute__((address_space(1))) unsigned int*)g,
      (__attribute__((address_space(3))) unsigned int*)l, 16, 0, 0);
}

// fast gelu: max abs err ~3e-4 << bf16 quantum
__device__ __forceinline__ float fast_gelu(float x) {
  float z = 0.7978845608f * (x + 0.044715f * x * x * x);
  float u = __expf(2.0f * z);
  float th = (u - 1.0f) * __builtin_amdgcn_rcpf(u + 1.0f);
  return 0.5f * x * (1.0f + th);
}

// pack in[R][C] f32 -> out[R/32][C][32] bf16
__global__ void k_pack(const float* __restrict__ in, bf16_t* __restrict__ out, int R, int C) {
  __shared__ float tile[64][65];
  const size_t mat = (size_t)blockIdx.z * R * C;
  in  += mat;
  out += mat;
  int r0 = blockIdx.y * 64, c0 = blockIdx.x * 64;
  for (int i = threadIdx.x; i < 4096; i += 256) {
    int r = i >> 6, c = i & 63;
    tile[r][c] = in[(size_t)(r0 + r) * C + c0 + c];
  }
  __syncthreads();
  int item = threadIdx.x >> 1, jh = threadIdx.x & 1;
  int c = item & 63, s = item >> 6;
  union { bf16_t h[16]; uint4 u[2]; } t;
#pragma unroll
  for (int k = 0; k < 16; k++) t.h[k] = (bf16_t)tile[s * 32 + jh * 16 + k][c];
  char* dst = (char*)out + ((size_t)((r0 >> 5) + s) * C + (c0 + c)) * 64 + jh * 32;
  ((uint4*)dst)[0] = t.u[0];
  ((uint4*)dst)[1] = t.u[1];
}

__global__ void k_tlog(const int* __restrict__ task_ids, const float* __restrict__ task_emb,
                       const float* __restrict__ gate_w, const float* __restrict__ gate_b,
                       double* __restrict__ tlog) {
  int i = threadIdx.x;
  if (i >= 64) return;
  int b = i >> 3, e = i & 7;
  const float* te = task_emb + (size_t)task_ids[b] * D_MODEL;
  double acc = (double)gate_b[e];
  for (int d = 0; d < D_MODEL; d++)
    acc += (double)te[d] * (double)gate_w[(size_t)(D_MODEL + d) * NEXP + e];
  tlog[i] = acc;
}

// one wave per token: f64 logits, top-2 softmax
__global__ void k_gate(const float* __restrict__ x, const float* __restrict__ gate_w,
                       const double* __restrict__ tlog,
                       float* __restrict__ logits_out,
                       int* __restrict__ toke, float2* __restrict__ tg,
                       float* __restrict__ omega) {
  int gtid = blockIdx.x * blockDim.x + threadIdx.x;
  int t = gtid >> 6;
  int lane = gtid & 63;
  if (t >= TOKENS) return;
  const float* xr = x + (size_t)t * D_MODEL;
  int d0 = lane * 8;
  float4 xa = *(const float4*)(xr + d0);
  float4 xc = *(const float4*)(xr + d0 + 4);
  float xv[8] = {xa.x, xa.y, xa.z, xa.w, xc.x, xc.y, xc.z, xc.w};
  double acc[NEXP];
#pragma unroll
  for (int e = 0; e < NEXP; e++) acc[e] = 0.0;
#pragma unroll
  for (int j = 0; j < 8; j++) {
    const float* gwr = gate_w + (size_t)(d0 + j) * NEXP;
    float4 g0 = *(const float4*)gwr;
    float4 g1 = *(const float4*)(gwr + 4);
    double xd = (double)xv[j];
    acc[0] += xd * (double)g0.x; acc[1] += xd * (double)g0.y;
    acc[2] += xd * (double)g0.z; acc[3] += xd * (double)g0.w;
    acc[4] += xd * (double)g1.x; acc[5] += xd * (double)g1.y;
    acc[6] += xd * (double)g1.z; acc[7] += xd * (double)g1.w;
  }
#pragma unroll
  for (int off = 32; off > 0; off >>= 1) {
#pragma unroll
    for (int e = 0; e < NEXP; e++) acc[e] += __shfl_xor(acc[e], off);
  }
  if (lane == 0) {
    int b = t >> 10;
    double lg[NEXP];
#pragma unroll
    for (int e = 0; e < NEXP; e++) {
      lg[e] = acc[e] + tlog[b * NEXP + e];
      logits_out[(size_t)t * NEXP + e] = (float)lg[e];
    }
    int e0 = 0;
    for (int e = 1; e < NEXP; e++) if (lg[e] > lg[e0]) e0 = e;
    int e1 = (e0 == 0) ? 1 : 0;
    for (int e = 0; e < NEXP; e++) if (e != e0 && lg[e] > lg[e1]) e1 = e;
    double p0 = 1.0 / (1.0 + exp(lg[e1] - lg[e0]));
    float g0f = (float)p0;
    float g1f = (float)(1.0 - p0);
    omega[t] = 1.0f - g0f;
    toke[t] = e0 | (e1 << 8);
    tg[t] = float2{g0f, g1f};
  }
}

__global__ void k_route(const int* __restrict__ toke, const float2* __restrict__ tg,
                        int* __restrict__ counts, int* __restrict__ tokl,
                        float* __restrict__ gatel) {
  __shared__ int lcnt[NEXP];
  __shared__ int lbase[NEXP];
  const int tid = threadIdx.x;
  if (tid < NEXP) lcnt[tid] = 0;
  __syncthreads();
  const int t = blockIdx.x * 256 + tid;
  const int pe = toke[t];
  const int e0 = pe & 0xff, e1 = pe >> 8;
  const float2 g = tg[t];
  const int r0 = atomicAdd(&lcnt[e0], 1);
  const int r1 = atomicAdd(&lcnt[e1], 1);
  __syncthreads();
  if (tid < NEXP) lbase[tid] = atomicAdd(counts + tid, lcnt[tid]);
  __syncthreads();
  int i0 = lbase[e0] + r0;
  tokl[e0 * TOKENS + i0]  = (t << 1);
  gatel[e0 * TOKENS + i0] = g.x;
  int i1 = lbase[e1] + r1;
  tokl[e1 * TOKENS + i1]  = (t << 1) | 1;
  gatel[e1 * TOKENS + i1] = g.y;
}

// section offsets (pad 256) + dense tile map: universal tiles first, then experts
__global__ void k_soff(const int* __restrict__ cnts, int* __restrict__ soff,
                       int* __restrict__ spc, int* __restrict__ tmap) {
  if (threadIdx.x == 0) {
    soff[8] = 0; spc[8] = TOKENS;
    int n = 0;
    for (int mt = 0; mt < 32; mt++) tmap[n++] = (8 << 8) | mt;
    int off = TOKENS;
    for (int e = 0; e < 8; e++) {
      int c = cnts[e];
      int p = (c + 255) & ~255;
      soff[e] = off; spc[e] = p;
      off += p;
      for (int mt = 0; mt < (p >> 8); mt++) tmap[n++] = (e << 8) | mt;
    }
    tmap[128] = n;
  }
}

__global__ void k_fill(const int* __restrict__ cnts, const int* __restrict__ soff,
                       const int* __restrict__ spc,
                       const int* __restrict__ tokl, const float* __restrict__ gatel,
                       const float* __restrict__ omega,
                       int* __restrict__ rmeta, float* __restrict__ rgate) {
  int r = blockIdx.x * 256 + threadIdx.x;
  if (r >= TROWS) return;
  if (r < TOKENS) { rmeta[r] = (r << 2) | 2; rgate[r] = omega[r]; return; }
  int meta = 3; float g = 0.f;
#pragma unroll
  for (int e = 0; e < 8; e++) {
    int off = soff[e];
    if (r >= off && r < off + spc[e]) {
      int i = r - off;
      if (i < cnts[e]) {
        int en = tokl[e * TOKENS + i];
        meta = ((en >> 1) << 2) | (en & 1);
        g = gatel[e * TOKENS + i];
      }
      break;
    }
  }
  rmeta[r] = meta; rgate[r] = g;
}

// gather X rows (f32 -> bf16) into k-slab layout xgp[s][row][32]
__global__ void k_gather(const float* __restrict__ x, const int* __restrict__ rmeta,
                         bf16_t* __restrict__ xgp) {
  int rbase = blockIdx.x * 128;
  for (int it = 0; it < 8; it++) {
    int id = it * 256 + threadIdx.x;
    int row = rbase + (id >> 4), s = id & 15;
    int meta = rmeta[row];
    union { bf16_t h[32]; uint4 u[4]; } t;
    if ((meta & 3) == 3) {
#pragma unroll
      for (int j = 0; j < 4; j++) t.u[j] = uint4{0, 0, 0, 0};
    } else {
      const float* src = x + (size_t)(meta >> 2) * D_MODEL + s * 32;
#pragma unroll
      for (int j = 0; j < 32; j += 4) {
        float4 v = *(const float4*)(src + j);
        t.h[j] = (bf16_t)v.x; t.h[j + 1] = (bf16_t)v.y;
        t.h[j + 2] = (bf16_t)v.z; t.h[j + 3] = (bf16_t)v.w;
      }
    }
    char* dst = (char*)xgp + ((size_t)s * TROWS + row) * 64;
#pragma unroll
    for (int j = 0; j < 4; j++) ((uint4*)dst)[j] = t.u[j];
  }
}

// ============================================================================
// 256x256 / BK=64 / 8-wave GEMM, 2 phases per K-tile, ONE barrier per phase.
// Per phase: {12 ds_read_b128 -> lgkmcnt(0) -> 32 MFMA -> vmcnt(8) -> barrier}
// with 2 stage regions (4 global_load_lds) issued between reads and the drain.
// Staging schedule (uniform): P0 of kt stages (kt+1, ks1); P1 stages
// (kt+2, ks0). Every phase ends vmcnt(8): retires exactly the 4 loads of the
// region needed NEXT phase, issued 3 phases earlier (deep latency budget).
// Safety: a region's stage-issue always follows the barrier that followed all
// waves' drained reads of that region (leading barrier provably redundant).
// Dense tile table (tmap) + sg-per-m-tile XCD swizzle: exact 13 tiles/XCD,
// all NT nt-sharers of an A-panel co-resident on one XCD (keeps R2's L2 win).
// ============================================================================
template <int KT, int NB, int EPI, int NT, int LOG2NT>
__global__ __launch_bounds__(512, 2) void k_gemm256(
    const bf16_t* __restrict__ Ab, const bf16_t* __restrict__ wEx,
    const bf16_t* __restrict__ wUn, const float* __restrict__ bEx,
    const float* __restrict__ bUn,
    const int* __restrict__ soff, const int* __restrict__ tmap,
    bf16_t* __restrict__ hpOut,
    const int* __restrict__ rmeta, const float* __restrict__ rgate,
    bf16_t* __restrict__ s0, bf16_t* __restrict__ s1, float* __restrict__ outF) {
  const int wg = blockIdx.x;
  const int xcd = wg & 7, j = wg >> 3;
  const int t = xcd + ((j >> LOG2NT) << 3);     // dense tile index, t%8 == xcd
  const int nt = j & (NT - 1);
  if (t >= tmap[128]) return;
  const int tm = tmap[t];
  const int sec = tm >> 8, mt = tm & 255;

  const int groff = soff[sec];
  const char* Bsec = (const char*)((sec == 8) ? wUn : (wEx + (size_t)sec * (2 * KT) * NB * 32));
  const float* bias = (sec == 8) ? bUn : (bEx + sec * NB);

  __shared__ char smem[131072];
  const int tid = threadIdx.x;
  const int wave = tid >> 6, lane = tid & 63;
  const int l16 = lane & 15, quad = lane >> 4;
  const int wm = wave >> 2, wn = wave & 3;

  // staging: thread covers chunks c = tid, tid+512 of each 16-KB region
  // chunk c -> LDS (row=c>>2, slot=c&3); source slot = slot ^ ((row>>1)&3)
  const int r0 = tid >> 2;
  const int ss = (tid & 3) ^ ((tid >> 3) & 3);
  const int grow0 = groff + mt * 256;
  const char* aSrc = (const char*)Ab + (size_t)(grow0 + r0) * 64 + ss * 16;
  const char* bSrc = Bsec + (size_t)(nt * 256 + r0) * 64 + ss * 16;
  char* ldsW = smem + wave * 1024;

  // fragment read offsets (swizzled)
  const int swz = ((quad ^ ((l16 >> 1) & 3)) << 4);
  const int aRd = (wm * 128 + l16) * 64 + swz;
  const int bRd = 32768 + (wn * 64 + l16) * 64 + swz;

  f32x4_t acc[8][4];
#pragma unroll
  for (int i = 0; i < 8; i++)
#pragma unroll
    for (int n = 0; n < 4; n++) acc[i][n] = f32x4_t{0.f, 0.f, 0.f, 0.f};

  auto stageA = [&](int kt, int ks) {
    const char* g = aSrc + (size_t)(2 * kt + ks) * ((size_t)TROWS * 64);
    char* l = ldsW + (kt & 1) * 65536 + ks * 16384;
    load_lds16(g, l);
    load_lds16(g + 8192, l + 8192);
  };
  auto stageB = [&](int kt, int ks) {
    const char* g = bSrc + (size_t)(2 * kt + ks) * ((size_t)NB * 64);
    char* l = ldsW + (kt & 1) * 65536 + 32768 + ks * 16384;
    load_lds16(g, l);
    load_lds16(g + 8192, l + 8192);
  };

  // one phase: reads (buf,ks), stages (stKt,stKs) unless stKt<0, MFMA 32, vmcnt(vm), barrier
  auto phase = [&](int kt, int ks, int stKt, int stKs, int vm) {
    const int buf = kt & 1;
    const char* base = smem + buf * 65536 + ks * 16384;
    bf16x8_t Ar[8], Br[4];
#pragma unroll
    for (int f = 0; f < 8; f++) Ar[f] = *(const bf16x8_t*)(base + aRd + f * 1024);
#pragma unroll
    for (int f = 0; f < 4; f++) Br[f] = *(const bf16x8_t*)(base + bRd + f * 1024);
    if (stKt >= 0) { stageA(stKt, stKs); stageB(stKt, stKs); }
    asm volatile("s_waitcnt lgkmcnt(0)" ::: "memory");
    __builtin_amdgcn_sched_barrier(0);
    __builtin_amdgcn_s_setprio(1);
#pragma unroll
    for (int mm = 0; mm < 8; mm++)
#pragma unroll
      for (int n = 0; n < 4; n++)
        acc[mm][n] = mfma_bf16(Br[n], Ar[mm], acc[mm][n]);  // swapped operands
    __builtin_amdgcn_s_setprio(0);
    if (vm == 8)      asm volatile("s_waitcnt vmcnt(8)" ::: "memory");
    else if (vm == 4) asm volatile("s_waitcnt vmcnt(4)" ::: "memory");
    else if (vm == 0) asm volatile("s_waitcnt vmcnt(0)" ::: "memory");
    __builtin_amdgcn_s_barrier();
  };

  // prologue: 12 loads (kt0 both halves + kt1 ks0); retire kt0.ks0
  stageA(0, 0); stageB(0, 0); stageA(0, 1); stageB(0, 1);
  stageA(1, 0); stageB(1, 0);
  asm volatile("s_waitcnt vmcnt(8)" ::: "memory");
  __builtin_amdgcn_s_barrier();

  for (int kt = 0; kt < KT - 2; ++kt) {
    phase(kt, 0, kt + 1, 1, 8);
    phase(kt, 1, kt + 2, 0, 8);
  }
  phase(KT - 2, 0, KT - 1, 1, 8);
  phase(KT - 2, 1, -1, 0, 4);
  phase(KT - 1, 0, -1, 0, 0);
  phase(KT - 1, 1, -1, 0, -1);

  // ---- epilogue: lane holds C[row = wm*128+mm*16+l16][col = nt*256+wn*64+n*16+quad*4 .. +3]
  const int colq = wn * 64 + quad * 4;
  float4 bv[4];
#pragma unroll
  for (int n = 0; n < 4; n++)
    bv[n] = *(const float4*)(bias + nt * 256 + colq + n * 16);

  if constexpr (EPI == 0) {
    // bias + gelu -> hp k-slab [slab][TROWS][32], packed 8-B stores
#pragma unroll
    for (int mm = 0; mm < 8; mm++) {
      const int row = grow0 + wm * 128 + mm * 16 + l16;
#pragma unroll
      for (int n = 0; n < 4; n++) {
        float b4[4] = {bv[n].x, bv[n].y, bv[n].z, bv[n].w};
        union { bf16_t h[4]; uint2 u; } t2;
#pragma unroll
        for (int i = 0; i < 4; i++)
          t2.h[i] = (bf16_t)fast_gelu(acc[mm][n][i] + b4[i]);
        char* dst = (char*)hpOut +
            ((size_t)(nt * 8 + wn * 2 + (n >> 1)) * TROWS + row) * 64 +
            (n & 1) * 32 + quad * 8;
        *(uint2*)dst = t2.u;
      }
    }
  } else {
    // +b2, *gate, scatter by slot
#pragma unroll
    for (int mm = 0; mm < 8; mm++) {
      const int grow = grow0 + wm * 128 + mm * 16 + l16;
      const int dbase = nt * 256 + colq;
      if (sec == 8) {
        const float g = rgate[grow];
        float* dst = outF + (size_t)grow * D_MODEL + dbase;
#pragma unroll
        for (int n = 0; n < 4; n++) {
          float b4[4] = {bv[n].x, bv[n].y, bv[n].z, bv[n].w};
          float4 o;
          o.x = (acc[mm][n][0] + b4[0]) * g;
          o.y = (acc[mm][n][1] + b4[1]) * g;
          o.z = (acc[mm][n][2] + b4[2]) * g;
          o.w = (acc[mm][n][3] + b4[3]) * g;
          *(float4*)(dst + n * 16) = o;
        }
      } else {
        const int meta = rmeta[grow];
        const int slot = meta & 3;
        if (slot == 3) continue;
        const float g = rgate[grow];
        bf16_t* dst = (slot ? s1 : s0) + (size_t)(meta >> 2) * D_MODEL + dbase;
#pragma unroll
        for (int n = 0; n < 4; n++) {
          float b4[4] = {bv[n].x, bv[n].y, bv[n].z, bv[n].w};
          union { bf16_t h[4]; uint2 u; } t2;
#pragma unroll
          for (int i = 0; i < 4; i++)
            t2.h[i] = (bf16_t)((acc[mm][n][i] + b4[i]) * g);
          *(uint2*)(dst + n * 16) = t2.u;
        }
      }
    }
  }
}

__global__ void k_combine(const bf16x4_t* __restrict__ s0, const bf16x4_t* __restrict__ s1,
                          float4* __restrict__ out, int n4) {
  int i = blockIdx.x * blockDim.x + threadIdx.x;
  if (i >= n4) return;
  bf16x4_t a = s0[i], b = s1[i];
  float4 o = out[i];
  o.x += (float)a[0] + (float)b[0];
  o.y += (float)a[1] + (float)b[1];
  o.z += (float)a[2] + (float)b[2];
  o.w += (float)a[3] + (float)b[3];
  out[i] = o;
}

extern "C" void kernel_launch(void* const* d_in, const int* in_sizes, int n_in,
                              void* d_out, int out_size, void* d_ws, size_t ws_size,
                              hipStream_t stream) {
  (void)in_sizes; (void)n_in; (void)out_size; (void)ws_size;
  const float* x        = (const float*)d_in[0];
  const int*   task_ids = (const int*)  d_in[1];
  const float* task_emb = (const float*)d_in[2];
  const float* gate_w   = (const float*)d_in[3];
  const float* gate_b   = (const float*)d_in[4];
  const float* w1       = (const float*)d_in[5];
  const float* b1       = (const float*)d_in[6];
  const float* w2       = (const float*)d_in[7];
  const float* b2       = (const float*)d_in[8];
  const float* uw1      = (const float*)d_in[9];
  const float* ub1      = (const float*)d_in[10];
  const float* uw2      = (const float*)d_in[11];
  const float* ub2      = (const float*)d_in[12];

  char* ws = (char*)d_ws;
  bf16_t* w1p   = (bf16_t*)(ws + W1P_OFF);
  bf16_t* uw1p  = (bf16_t*)(ws + UW1P_OFF);
  bf16_t* w2p   = (bf16_t*)(ws + W2P_OFF);
  bf16_t* uw2p  = (bf16_t*)(ws + UW2P_OFF);
  bf16_t* s0    = (bf16_t*)(ws + S0_OFF);
  bf16_t* s1    = (bf16_t*)(ws + S1_OFF);
  int*    cnts  = (int*)   (ws + CNT_OFF);
  int*    tokl  = (int*)   (ws + TOKL_OFF);
  float*  gatel = (float*) (ws + GATEL_OFF);
  float*  omg   = (float*) (ws + OMEGA_OFF);
  double* tlog  = (double*)(ws + TLOG_OFF);
  int*    soff  = (int*)   (ws + SOFF_OFF);
  int*    spc   = (int*)   (ws + SPC_OFF);
  int*    rmeta = (int*)   (ws + RMETA_OFF);
  float*  rgate = (float*) (ws + RGATE_OFF);
  bf16_t* xgp   = (bf16_t*)(ws + XGP_OFF);
  bf16_t* hp    = (bf16_t*)(ws + HP_OFF);
  int*    toke  = (int*)   (ws + TOKE_OFF);
  float2* tg    = (float2*)(ws + TG_OFF);
  int*    tmap  = (int*)   (ws + TMAP_OFF);

  float* out    = (float*)d_out;
  float* logits = out + (size_t)TOKENS * D_MODEL;

  hipMemsetAsync(cnts, 0, 64, stream);

  k_pack<<<dim3(32, 8, NEXP), 256, 0, stream>>>(w1, w1p, D_MODEL, D_FF);
  k_pack<<<dim3(8, 32, NEXP), 256, 0, stream>>>(w2, w2p, D_FF, D_MODEL);
  k_pack<<<dim3(32, 8, 1),    256, 0, stream>>>(uw1, uw1p, D_MODEL, D_FF);
  k_pack<<<dim3(8, 32, 1),    256, 0, stream>>>(uw2, uw2p, D_FF, D_MODEL);
  k_tlog<<<1, 64, 0, stream>>>(task_ids, task_emb, gate_w, gate_b, tlog);
  k_gate<<<dim3(TOKENS / 4), 256, 0, stream>>>(x, gate_w, tlog, logits, toke, tg, omg);
  k_route<<<dim3(TOKENS / 256), 256, 0, stream>>>(toke, tg, cnts, tokl, gatel);
  k_soff<<<1, 64, 0, stream>>>(cnts, soff, spc, tmap);
  k_fill<<<dim3((TROWS + 255) / 256), 256, 0, stream>>>(cnts, soff, spc, tokl, gatel, omg,
                                                        rmeta, rgate);
  k_gather<<<dim3(TROWS / 128), 256, 0, stream>>>(x, rmeta, xgp);
  // dense grids: max 104 m-tiles (32 universal + <=72 expert)
  k_gemm256<8, D_FF, 0, 8, 3><<<dim3(104 * 8), 512, 0, stream>>>(
      xgp, w1p, uw1p, b1, ub1, soff, tmap, hp,
      nullptr, nullptr, nullptr, nullptr, nullptr);
  k_gemm256<32, D_MODEL, 1, 2, 1><<<dim3(104 * 2), 512, 0, stream>>>(
      hp, w2p, uw2p, b2, ub2, soff, tmap, nullptr,
      rmeta, rgate, s0, s1, out);
  const int n4 = TOKENS * D_MODEL / 4;
  k_combine<<<dim3(n4 / 256), 256, 0, stream>>>((const bf16x4_t*)s0, (const bf16x4_t*)s1,
                                                (float4*)out, n4);
}

// Round 5
// 375.709 us; speedup vs baseline: 1.5335x; 1.0719x over previous
//
#include <hip/hip_runtime.h>

#define D_MODEL 512
#define D_FF    2048
#define NEXP    8
#define TOKENS  8192
#define TROWS   26368     // 8192 universal + <=18176 expert slots padded to 256

typedef __bf16 bf16_t;
typedef __attribute__((ext_vector_type(8))) __bf16 bf16x8_t;
typedef __attribute__((ext_vector_type(4))) __bf16 bf16x4_t;
typedef __attribute__((ext_vector_type(4))) float  f32x4_t;

// ---- workspace layout (bytes) ----
#define W1P_OFF    0u            // bf16 [16][2048][32] x8 experts
#define UW1P_OFF   16777216u     // bf16 [16][2048][32]
#define W2P_OFF    18874368u     // bf16 [64][512][32] x8
#define UW2P_OFF   35651584u     // bf16 [64][512][32]
#define CNT_OFF    37748736u     // int[16]
#define TOKL_OFF   37748800u     // int  [8][8192]
#define GATEL_OFF  38010944u     // float[8][8192]
#define OMEGA_OFF  38273088u     // float[8192]
#define TLOG_OFF   38305856u     // double[8][8]
#define SOFF_OFF   38306368u     // int[16]
#define SPC_OFF    38306432u     // int[16]
#define RMETA_OFF  38306496u     // int[TROWS]
#define RGATE_OFF  38411968u     // float[TROWS]
#define XGP_OFF    38517440u     // bf16 [16][TROWS][32]
#define S0_OFF     38517440u     // ALIAS of XGP (xgp dead before gemm2 writes s0/s1)
#define S1_OFF     46906048u     // ALIAS of XGP
#define HP_OFF     65517248u     // bf16 [64][TROWS][32]
#define TOKE_OFF   173516480u    // int[8192]
#define TG_OFF     173549248u    // float2[8192]
#define TMAP_OFF   173614784u    // int[136]

__device__ inline f32x4_t mfma_bf16(bf16x8_t a, bf16x8_t b, f32x4_t c) {
  return __builtin_amdgcn_mfma_f32_16x16x32_bf16(a, b, c, 0, 0, 0);
}

__device__ __forceinline__ void load_lds16(const void* g, void* l) {
  __builtin_amdgcn_global_load_lds(
      (const __attribute__((address_space(1))) unsigned int*)g,
      (__attribute__((address_space(3))) unsigned int*)l, 16, 0, 0);
}

// fast gelu: max abs err ~3e-4 << bf16 quantum
__device__ __forceinline__ float fast_gelu(float x) {
  float z = 0.7978845608f * (x + 0.044715f * x * x * x);
  float u = __expf(2.0f * z);
  float th = (u - 1.0f) * __builtin_amdgcn_rcpf(u + 1.0f);
  return 0.5f * x * (1.0f + th);
}

// pack in[R][C] f32 -> out[R/32][C][32] bf16, LDS-free (reads coalesced per-k)
__global__ void k_pack(const float* __restrict__ in, bf16_t* __restrict__ out, int R, int C) {
  const size_t mat = (size_t)blockIdx.z * R * C;
  in  += mat;
  out += mat;
  int r0 = blockIdx.y * 64, c0 = blockIdx.x * 64;
  int item = threadIdx.x >> 1, jh = threadIdx.x & 1;
  int c = item & 63, s = item >> 6;
  const float* src = in + (size_t)(r0 + s * 32 + jh * 16) * C + (c0 + c);
  union { bf16_t h[16]; uint4 u[2]; } t;
#pragma unroll
  for (int k = 0; k < 16; k++) t.h[k] = (bf16_t)src[(size_t)k * C];
  char* dst = (char*)out + ((size_t)((r0 >> 5) + s) * C + (c0 + c)) * 64 + jh * 32;
  ((uint4*)dst)[0] = t.u[0];
  ((uint4*)dst)[1] = t.u[1];
}

__global__ void k_tlog(const int* __restrict__ task_ids, const float* __restrict__ task_emb,
                       const float* __restrict__ gate_w, const float* __restrict__ gate_b,
                       double* __restrict__ tlog) {
  int i = threadIdx.x;
  if (i >= 64) return;
  int b = i >> 3, e = i & 7;
  const float* te = task_emb + (size_t)task_ids[b] * D_MODEL;
  double acc = (double)gate_b[e];
  for (int d = 0; d < D_MODEL; d++)
    acc += (double)te[d] * (double)gate_w[(size_t)(D_MODEL + d) * NEXP + e];
  tlog[i] = acc;
}

// one wave per token: f64 logits, top-2 softmax
__global__ void k_gate(const float* __restrict__ x, const float* __restrict__ gate_w,
                       const double* __restrict__ tlog,
                       float* __restrict__ logits_out,
                       int* __restrict__ toke, float2* __restrict__ tg,
                       float* __restrict__ omega) {
  int gtid = blockIdx.x * blockDim.x + threadIdx.x;
  int t = gtid >> 6;
  int lane = gtid & 63;
  if (t >= TOKENS) return;
  const float* xr = x + (size_t)t * D_MODEL;
  int d0 = lane * 8;
  float4 xa = *(const float4*)(xr + d0);
  float4 xc = *(const float4*)(xr + d0 + 4);
  float xv[8] = {xa.x, xa.y, xa.z, xa.w, xc.x, xc.y, xc.z, xc.w};
  double acc[NEXP];
#pragma unroll
  for (int e = 0; e < NEXP; e++) acc[e] = 0.0;
#pragma unroll
  for (int j = 0; j < 8; j++) {
    const float* gwr = gate_w + (size_t)(d0 + j) * NEXP;
    float4 g0 = *(const float4*)gwr;
    float4 g1 = *(const float4*)(gwr + 4);
    double xd = (double)xv[j];
    acc[0] += xd * (double)g0.x; acc[1] += xd * (double)g0.y;
    acc[2] += xd * (double)g0.z; acc[3] += xd * (double)g0.w;
    acc[4] += xd * (double)g1.x; acc[5] += xd * (double)g1.y;
    acc[6] += xd * (double)g1.z; acc[7] += xd * (double)g1.w;
  }
#pragma unroll
  for (int off = 32; off > 0; off >>= 1) {
#pragma unroll
    for (int e = 0; e < NEXP; e++) acc[e] += __shfl_xor(acc[e], off);
  }
  if (lane == 0) {
    int b = t >> 10;
    double lg[NEXP];
#pragma unroll
    for (int e = 0; e < NEXP; e++) {
      lg[e] = acc[e] + tlog[b * NEXP + e];
      logits_out[(size_t)t * NEXP + e] = (float)lg[e];
    }
    int e0 = 0;
    for (int e = 1; e < NEXP; e++) if (lg[e] > lg[e0]) e0 = e;
    int e1 = (e0 == 0) ? 1 : 0;
    for (int e = 0; e < NEXP; e++) if (e != e0 && lg[e] > lg[e1]) e1 = e;
    double p0 = 1.0 / (1.0 + exp(lg[e1] - lg[e0]));
    float g0f = (float)p0;
    float g1f = (float)(1.0 - p0);
    omega[t] = 1.0f - g0f;
    toke[t] = e0 | (e1 << 8);
    tg[t] = float2{g0f, g1f};
  }
}

__global__ void k_route(const int* __restrict__ toke, const float2* __restrict__ tg,
                        int* __restrict__ counts, int* __restrict__ tokl,
                        float* __restrict__ gatel) {
  __shared__ int lcnt[NEXP];
  __shared__ int lbase[NEXP];
  const int tid = threadIdx.x;
  if (tid < NEXP) lcnt[tid] = 0;
  __syncthreads();
  const int t = blockIdx.x * 256 + tid;
  const int pe = toke[t];
  const int e0 = pe & 0xff, e1 = pe >> 8;
  const float2 g = tg[t];
  const int r0 = atomicAdd(&lcnt[e0], 1);
  const int r1 = atomicAdd(&lcnt[e1], 1);
  __syncthreads();
  if (tid < NEXP) lbase[tid] = atomicAdd(counts + tid, lcnt[tid]);
  __syncthreads();
  int i0 = lbase[e0] + r0;
  tokl[e0 * TOKENS + i0]  = (t << 1);
  gatel[e0 * TOKENS + i0] = g.x;
  int i1 = lbase[e1] + r1;
  tokl[e1 * TOKENS + i1]  = (t << 1) | 1;
  gatel[e1 * TOKENS + i1] = g.y;
}

// section offsets (pad 256) + dense tile map
__global__ void k_soff(const int* __restrict__ cnts, int* __restrict__ soff,
                       int* __restrict__ spc, int* __restrict__ tmap) {
  if (threadIdx.x == 0) {
    soff[8] = 0; spc[8] = TOKENS;
    int n = 0;
    for (int mt = 0; mt < 32; mt++) tmap[n++] = (8 << 8) | mt;
    int off = TOKENS;
    for (int e = 0; e < 8; e++) {
      int c = cnts[e];
      int p = (c + 255) & ~255;
      soff[e] = off; spc[e] = p;
      off += p;
      for (int mt = 0; mt < (p >> 8); mt++) tmap[n++] = (e << 8) | mt;
    }
    tmap[128] = n;
  }
}

__global__ void k_fill(const int* __restrict__ cnts, const int* __restrict__ soff,
                       const int* __restrict__ spc,
                       const int* __restrict__ tokl, const float* __restrict__ gatel,
                       const float* __restrict__ omega,
                       int* __restrict__ rmeta, float* __restrict__ rgate) {
  int r = blockIdx.x * 256 + threadIdx.x;
  if (r >= TROWS) return;
  if (r < TOKENS) { rmeta[r] = (r << 2) | 2; rgate[r] = omega[r]; return; }
  int meta = 3; float g = 0.f;
#pragma unroll
  for (int e = 0; e < 8; e++) {
    int off = soff[e];
    if (r >= off && r < off + spc[e]) {
      int i = r - off;
      if (i < cnts[e]) {
        int en = tokl[e * TOKENS + i];
        meta = ((en >> 1) << 2) | (en & 1);
        g = gatel[e * TOKENS + i];
      }
      break;
    }
  }
  rmeta[r] = meta; rgate[r] = g;
}

// gather X rows (f32 -> bf16) into k-slab layout xgp[s][row][32]
__global__ void k_gather(const float* __restrict__ x, const int* __restrict__ rmeta,
                         bf16_t* __restrict__ xgp) {
  int rbase = blockIdx.x * 128;
  for (int it = 0; it < 8; it++) {
    int id = it * 256 + threadIdx.x;
    int row = rbase + (id >> 4), s = id & 15;
    int meta = rmeta[row];
    union { bf16_t h[32]; uint4 u[4]; } t;
    if ((meta & 3) == 3) {
#pragma unroll
      for (int j = 0; j < 4; j++) t.u[j] = uint4{0, 0, 0, 0};
    } else {
      const float* src = x + (size_t)(meta >> 2) * D_MODEL + s * 32;
#pragma unroll
      for (int j = 0; j < 32; j += 4) {
        float4 v = *(const float4*)(src + j);
        t.h[j] = (bf16_t)v.x; t.h[j + 1] = (bf16_t)v.y;
        t.h[j + 2] = (bf16_t)v.z; t.h[j + 3] = (bf16_t)v.w;
      }
    }
    char* dst = (char*)xgp + ((size_t)s * TROWS + row) * 64;
#pragma unroll
    for (int j = 0; j < 4; j++) ((uint4*)dst)[j] = t.u[j];
  }
}

// ============================================================================
// 256x128 / BK=32 / 8-wave / 72-KiB-LDS GEMM, 2 blocks per CU (TLP overlap).
// LDS: A sets [3][256][64B] at 0; B sets [3][128][64B] at 49152. 3-deep
// rotation: kt reads set kt%3, stages kt+2 into (kt+2)%3 (= set last read at
// kt-1, whose readers drained at kt-1's lgkmcnt(0), before the kt-1 end
// barrier; stage issued after that barrier). Per kt, per wave: 8 ds_read_b128
// -> lgkmcnt(0) -> 16 MFMA -> vmcnt(3) -> 1 barrier; 3 stage loads (A:2, B:1)
// issued between reads and the lgkm drain. vmcnt(3) retires exactly the set
// needed next kt (issued 2 kts earlier). Never vmcnt(0) mid-loop.
// R4 BUG FIXED: bRd no longer includes the 49152 B-region base (bbase already
// adds it); R4 double-added it -> B fragments read past the LDS allocation.
// ============================================================================
template <int KT, int NB, int EPI, int NT, int LOG2NT>
__global__ __launch_bounds__(512, 4) void k_gemm(
    const bf16_t* __restrict__ Ab, const bf16_t* __restrict__ wEx,
    const bf16_t* __restrict__ wUn, const float* __restrict__ bEx,
    const float* __restrict__ bUn,
    const int* __restrict__ soff, const int* __restrict__ tmap,
    bf16_t* __restrict__ hpOut,
    const int* __restrict__ rmeta, const float* __restrict__ rgate,
    bf16_t* __restrict__ s0, bf16_t* __restrict__ s1, float* __restrict__ outF) {
  const int wg = blockIdx.x;
  const int xcd = wg & 7, j = wg >> 3;
  const int t = xcd + ((j >> LOG2NT) << 3);     // dense tile index, t%8 == xcd
  const int nt = j & (NT - 1);
  if (t >= tmap[128]) return;
  const int tm = tmap[t];
  const int sec = tm >> 8, mt = tm & 255;

  const int groff = soff[sec];
  const char* Bsec = (const char*)((sec == 8) ? wUn : (wEx + (size_t)sec * KT * NB * 32));
  const float* bias = (sec == 8) ? bUn : (bEx + sec * NB);

  __shared__ char smem[73728];
  const int tid = threadIdx.x;
  const int wave = tid >> 6, lane = tid & 63;
  const int l16 = lane & 15, quad = lane >> 4;
  const int wm = wave >> 1, wn = wave & 1;

  // staging: A region 16KB (256 rows x 64B): thread covers chunks tid, tid+512
  // B region 8KB (128 rows x 64B): chunk tid. chunk c -> (row=c>>2, slot=c&3);
  // source slot = slot ^ ((row>>1)&3)  (inverse swizzle on global side)
  const int r0 = tid >> 2;
  const int ss = (tid & 3) ^ ((tid >> 3) & 3);
  const int grow0 = groff + mt * 256;
  const char* aSrc = (const char*)Ab + (size_t)(grow0 + r0) * 64 + ss * 16;
  const char* bSrc = Bsec + (size_t)(nt * 128 + r0) * 64 + ss * 16;
  char* ldsWA = smem + wave * 1024;
  char* ldsWB = smem + 49152 + wave * 1024;

  // fragment read offsets (swizzled); bRd is RELATIVE to the B-region base
  const int swz = ((quad ^ ((l16 >> 1) & 3)) << 4);
  const int aRd = (wm * 64 + l16) * 64 + swz;
  const int bRd = (wn * 64 + l16) * 64 + swz;

  f32x4_t acc[4][4];
#pragma unroll
  for (int i = 0; i < 4; i++)
#pragma unroll
    for (int n = 0; n < 4; n++) acc[i][n] = f32x4_t{0.f, 0.f, 0.f, 0.f};

  auto stage = [&](int kt, int set) {
    const char* ga = aSrc + (size_t)kt * ((size_t)TROWS * 64);
    char* la = ldsWA + set * 16384;
    load_lds16(ga, la);
    load_lds16(ga + 8192, la + 8192);
    load_lds16(bSrc + (size_t)kt * ((size_t)NB * 64), ldsWB + set * 8192);
  };

  // prologue
  stage(0, 0); stage(1, 1);
  asm volatile("s_waitcnt vmcnt(3)" ::: "memory");
  __builtin_amdgcn_s_barrier();

  int rs = 0, ws = 2;
  for (int kt = 0; kt < KT; ++kt) {
    const char* abase = smem + rs * 16384;
    const char* bbase = smem + 49152 + rs * 8192;
    bf16x8_t Ar[4], Br[4];
#pragma unroll
    for (int f = 0; f < 4; f++) Ar[f] = *(const bf16x8_t*)(abase + aRd + f * 1024);
#pragma unroll
    for (int f = 0; f < 4; f++) Br[f] = *(const bf16x8_t*)(bbase + bRd + f * 1024);
    if (kt < KT - 2) stage(kt + 2, ws);
    asm volatile("s_waitcnt lgkmcnt(0)" ::: "memory");
    __builtin_amdgcn_sched_barrier(0);
    __builtin_amdgcn_s_setprio(1);
#pragma unroll
    for (int mm = 0; mm < 4; mm++)
#pragma unroll
      for (int n = 0; n < 4; n++)
        acc[mm][n] = mfma_bf16(Br[n], Ar[mm], acc[mm][n]);  // swapped operands
    __builtin_amdgcn_s_setprio(0);
    if (kt < KT - 2)       asm volatile("s_waitcnt vmcnt(3)" ::: "memory");
    else if (kt == KT - 2) asm volatile("s_waitcnt vmcnt(0)" ::: "memory");
    if (kt < KT - 1) __builtin_amdgcn_s_barrier();
    if (++rs == 3) rs = 0;
    if (++ws == 3) ws = 0;
  }

  // ---- epilogue: lane holds C[row = wm*64+mm*16+l16][col = nt*128+wn*64+n*16+quad*4 .. +3]
  const int colq = wn * 64 + quad * 4;
  float4 bv[4];
#pragma unroll
  for (int n = 0; n < 4; n++)
    bv[n] = *(const float4*)(bias + nt * 128 + colq + n * 16);

  if constexpr (EPI == 0) {
    // bias + gelu -> hp k-slab [slab][TROWS][32], packed 8-B stores
#pragma unroll
    for (int mm = 0; mm < 4; mm++) {
      const int row = grow0 + wm * 64 + mm * 16 + l16;
#pragma unroll
      for (int n = 0; n < 4; n++) {
        float b4[4] = {bv[n].x, bv[n].y, bv[n].z, bv[n].w};
        union { bf16_t h[4]; uint2 u; } t2;
#pragma unroll
        for (int i = 0; i < 4; i++)
          t2.h[i] = (bf16_t)fast_gelu(acc[mm][n][i] + b4[i]);
        char* dst = (char*)hpOut +
            ((size_t)(nt * 4 + wn * 2 + (n >> 1)) * TROWS + row) * 64 +
            (n & 1) * 32 + quad * 8;
        *(uint2*)dst = t2.u;
      }
    }
  } else {
    // +b2, *gate, scatter by slot
#pragma unroll
    for (int mm = 0; mm < 4; mm++) {
      const int grow = grow0 + wm * 64 + mm * 16 + l16;
      const int dbase = nt * 128 + colq;
      if (sec == 8) {
        const float g = rgate[grow];
        float* dst = outF + (size_t)grow * D_MODEL + dbase;
#pragma unroll
        for (int n = 0; n < 4; n++) {
          float b4[4] = {bv[n].x, bv[n].y, bv[n].z, bv[n].w};
          float4 o;
          o.x = (acc[mm][n][0] + b4[0]) * g;
          o.y = (acc[mm][n][1] + b4[1]) * g;
          o.z = (acc[mm][n][2] + b4[2]) * g;
          o.w = (acc[mm][n][3] + b4[3]) * g;
          *(float4*)(dst + n * 16) = o;
        }
      } else {
        const int meta = rmeta[grow];
        const int slot = meta & 3;
        if (slot == 3) continue;
        const float g = rgate[grow];
        bf16_t* dst = (slot ? s1 : s0) + (size_t)(meta >> 2) * D_MODEL + dbase;
#pragma unroll
        for (int n = 0; n < 4; n++) {
          float b4[4] = {bv[n].x, bv[n].y, bv[n].z, bv[n].w};
          union { bf16_t h[4]; uint2 u; } t2;
#pragma unroll
          for (int i = 0; i < 4; i++)
            t2.h[i] = (bf16_t)((acc[mm][n][i] + b4[i]) * g);
          *(uint2*)(dst + n * 16) = t2.u;
        }
      }
    }
  }
}

__global__ void k_combine(const bf16x4_t* __restrict__ s0, const bf16x4_t* __restrict__ s1,
                          float4* __restrict__ out, int n4) {
  int i = blockIdx.x * blockDim.x + threadIdx.x;
  if (i >= n4) return;
  bf16x4_t a = s0[i], b = s1[i];
  float4 o = out[i];
  o.x += (float)a[0] + (float)b[0];
  o.y += (float)a[1] + (float)b[1];
  o.z += (float)a[2] + (float)b[2];
  o.w += (float)a[3] + (float)b[3];
  out[i] = o;
}

extern "C" void kernel_launch(void* const* d_in, const int* in_sizes, int n_in,
                              void* d_out, int out_size, void* d_ws, size_t ws_size,
                              hipStream_t stream) {
  (void)in_sizes; (void)n_in; (void)out_size; (void)ws_size;
  const float* x        = (const float*)d_in[0];
  const int*   task_ids = (const int*)  d_in[1];
  const float* task_emb = (const float*)d_in[2];
  const float* gate_w   = (const float*)d_in[3];
  const float* gate_b   = (const float*)d_in[4];
  const float* w1       = (const float*)d_in[5];
  const float* b1       = (const float*)d_in[6];
  const float* w2       = (const float*)d_in[7];
  const float* b2       = (const float*)d_in[8];
  const float* uw1      = (const float*)d_in[9];
  const float* ub1      = (const float*)d_in[10];
  const float* uw2      = (const float*)d_in[11];
  const float* ub2      = (const float*)d_in[12];

  char* ws = (char*)d_ws;
  bf16_t* w1p   = (bf16_t*)(ws + W1P_OFF);
  bf16_t* uw1p  = (bf16_t*)(ws + UW1P_OFF);
  bf16_t* w2p   = (bf16_t*)(ws + W2P_OFF);
  bf16_t* uw2p  = (bf16_t*)(ws + UW2P_OFF);
  bf16_t* s0    = (bf16_t*)(ws + S0_OFF);
  bf16_t* s1    = (bf16_t*)(ws + S1_OFF);
  int*    cnts  = (int*)   (ws + CNT_OFF);
  int*    tokl  = (int*)   (ws + TOKL_OFF);
  float*  gatel = (float*) (ws + GATEL_OFF);
  float*  omg   = (float*) (ws + OMEGA_OFF);
  double* tlog  = (double*)(ws + TLOG_OFF);
  int*    soff  = (int*)   (ws + SOFF_OFF);
  int*    spc   = (int*)   (ws + SPC_OFF);
  int*    rmeta = (int*)   (ws + RMETA_OFF);
  float*  rgate = (float*) (ws + RGATE_OFF);
  bf16_t* xgp   = (bf16_t*)(ws + XGP_OFF);
  bf16_t* hp    = (bf16_t*)(ws + HP_OFF);
  int*    toke  = (int*)   (ws + TOKE_OFF);
  float2* tg    = (float2*)(ws + TG_OFF);
  int*    tmap  = (int*)   (ws + TMAP_OFF);

  float* out    = (float*)d_out;
  float* logits = out + (size_t)TOKENS * D_MODEL;

  hipMemsetAsync(cnts, 0, 64, stream);

  k_pack<<<dim3(32, 8, NEXP), 256, 0, stream>>>(w1, w1p, D_MODEL, D_FF);
  k_pack<<<dim3(8, 32, NEXP), 256, 0, stream>>>(w2, w2p, D_FF, D_MODEL);
  k_pack<<<dim3(32, 8, 1),    256, 0, stream>>>(uw1, uw1p, D_MODEL, D_FF);
  k_pack<<<dim3(8, 32, 1),    256, 0, stream>>>(uw2, uw2p, D_FF, D_MODEL);
  k_tlog<<<1, 64, 0, stream>>>(task_ids, task_emb, gate_w, gate_b, tlog);
  k_gate<<<dim3(TOKENS / 4), 256, 0, stream>>>(x, gate_w, tlog, logits, toke, tg, omg);
  k_route<<<dim3(TOKENS / 256), 256, 0, stream>>>(toke, tg, cnts, tokl, gatel);
  k_soff<<<1, 64, 0, stream>>>(cnts, soff, spc, tmap);
  k_fill<<<dim3((TROWS + 255) / 256), 256, 0, stream>>>(cnts, soff, spc, tokl, gatel, omg,
                                                        rmeta, rgate);
  k_gather<<<dim3(TROWS / 128), 256, 0, stream>>>(x, rmeta, xgp);
  // dense grids: max 104 m-tiles; gemm1: 16 nt of 128; gemm2: 4 nt of 128
  k_gemm<16, D_FF, 0, 16, 4><<<dim3(104 * 16), 512, 0, stream>>>(
      xgp, w1p, uw1p, b1, ub1, soff, tmap, hp,
      nullptr, nullptr, nullptr, nullptr, nullptr);
  k_gemm<64, D_MODEL, 1, 4, 2><<<dim3(104 * 4), 512, 0, stream>>>(
      hp, w2p, uw2p, b2, ub2, soff, tmap, nullptr,
      rmeta, rgate, s0, s1, out);
  const int n4 = TOKENS * D_MODEL / 4;
  k_combine<<<dim3(n4 / 256), 256, 0, stream>>>((const bf16x4_t*)s0, (const bf16x4_t*)s1,
                                                (float4*)out, n4);
}